// Round 19
// baseline (134.489 us; speedup 1.0000x reference)
//
#include <hip/hip_runtime.h>
#include <stdint.h>

typedef __attribute__((ext_vector_type(4))) float f32x4;
typedef __attribute__((ext_vector_type(16))) float f32x16;
typedef __attribute__((ext_vector_type(8))) short short8;
typedef __attribute__((ext_vector_type(4))) short short4v;

__device__ __forceinline__ short f2bf(float f) {
    union { float f; unsigned u; } x; x.f = f;
    return (short)((x.u + 0x7fffu + ((x.u >> 16) & 1u)) >> 16);
}

__device__ __forceinline__ unsigned cvt_pk_bf16(float lo, float hi) {
    unsigned r;
    asm("v_cvt_pk_bf16_f32 %0, %1, %2" : "=v"(r) : "v"(lo), "v"(hi));
    return r;
}

__device__ __forceinline__ float fexp2(float x) {
#if __has_builtin(__builtin_amdgcn_exp2f)
    return __builtin_amdgcn_exp2f(x);
#else
    return exp2f(x);
#endif
}

#define MFMA16(a, b, c) __builtin_amdgcn_mfma_f32_16x16x32_bf16((a), (b), (c), 0, 0, 0)
#define MFMA32(a, b, c) __builtin_amdgcn_mfma_f32_32x32x16_bf16((a), (b), (c), 0, 0, 0)

__device__ __forceinline__ void gload16(const void* g, void* l) {
    __builtin_amdgcn_global_load_lds((const __attribute__((address_space(1))) void*)g,
                                     (__attribute__((address_space(3))) void*)l, 16, 0, 0);
}

// all three f32->bf16 casts in one launch
__global__ __launch_bounds__(256) void cast_all(const float* __restrict__ h,
                                                const float* __restrict__ wq,
                                                const float* __restrict__ wo,
                                                short* __restrict__ hb,
                                                short* __restrict__ wqb,
                                                short* __restrict__ wob) {
    int i = blockIdx.x * 256 + threadIdx.x;  // 1048576 chunks of 8
    const float* s;
    short* d;
    int j;
    if (i < 524288) { s = h; d = hb; j = i; }
    else if (i < 917504) { s = wq; d = wqb; j = i - 524288; }
    else { s = wo; d = wob; j = i - 917504; }
    float4 a = ((const float4*)s)[j * 2];
    float4 b = ((const float4*)s)[j * 2 + 1];
    short8 o;
    o[0] = f2bf(a.x); o[1] = f2bf(a.y); o[2] = f2bf(a.z); o[3] = f2bf(a.w);
    o[4] = f2bf(b.x); o[5] = f2bf(b.y); o[6] = f2bf(b.z); o[7] = f2bf(b.w);
    ((short8*)d)[j] = o;
}

// ------------------- 8-phase 256x256 GEMM (C = A * B^T) -------------------
// QSCALE: scale cols [0,1024) by log2e. VFUSE: for n0>=2048 (V region) write
// transposed into vt[bh][d][s] instead of C (fuses the old transpose_v pass).
template <int OUT_BF16, int QSCALE, int VFUSE>
__global__ __launch_bounds__(512, 2) void gemm8p(const short* __restrict__ A,
                                                 const short* __restrict__ B,
                                                 void* __restrict__ Cout,
                                                 short* __restrict__ vt,
                                                 int M, int N, int K) {
    __shared__ short lds[2][4][8192];  // 128 KB
    const int t = threadIdx.x;
    const int l = t & 63, w = t >> 6;
    const int lr = l & 15, lg = l >> 4;
    const int wr = w >> 2, wc = w & 3;
    const int m0 = blockIdx.y * 256, n0 = blockIdx.x * 256;
    const int nt = K >> 6, nh = nt << 2;

    const int sr0 = t >> 2;
    const int scc = ((t & 3) ^ ((sr0 >> 1) & 3)) * 8;
    const short* As0 = A + (size_t)(m0 + sr0) * K + scc;
    const short* As1 = A + (size_t)(m0 + sr0 + 128) * K + scc;
    const short* Bs0 = B + (size_t)(n0 + sr0) * K + scc;
    const short* Bs1 = B + (size_t)(n0 + sr0 + 128) * K + scc;
    short* ldsb = &lds[0][0][0];

    auto stageH = [&](int H) {
        int Tp = H >> 2, pos = H & 3;
        int kb = Tp * 64 + ((pos <= 1) ? 32 : 0);
        short* dst = ldsb + ((Tp & 1) * 4 + pos) * 8192 + t * 8;
        if (pos & 1) {
            gload16(As0 + kb, dst);
            gload16(As1 + kb, dst + 4096);
        } else {
            gload16(Bs0 + kb, dst);
            gload16(Bs1 + kb, dst + 4096);
        }
    };

    int aoff[8], boff[4];
    #pragma unroll
    for (int mi = 0; mi < 8; ++mi) {
        int row = wr * 128 + mi * 16 + lr;
        aoff[mi] = row * 32 + (lg ^ ((row >> 1) & 3)) * 8;
    }
    #pragma unroll
    for (int ni = 0; ni < 4; ++ni) {
        int row = wc * 64 + ni * 16 + lr;
        boff[ni] = row * 32 + (lg ^ ((row >> 1) & 3)) * 8;
    }

    f32x4 acc[8][4] = {};

    for (int H = 0; H < 7; ++H) stageH(H);
    asm volatile("s_waitcnt vmcnt(6)" ::: "memory");
    __builtin_amdgcn_s_barrier();

    for (int T = 0; T < nt; ++T) {
        const short* rbase = ldsb + (T & 1) * 32768;
        const short* B1b = rbase;
        const short* A1b = rbase + 8192;
        const short* B0b = rbase + 16384;
        const short* A0b = rbase + 24576;
        const int Hs = (T << 2) + 7;
        short8 a[4], b[4];

        // ---- phase 0: k[32:64), m0-3 ----
        #pragma unroll
        for (int i = 0; i < 4; ++i) a[i] = *(const short8*)(A1b + aoff[i]);
        #pragma unroll
        for (int i = 0; i < 4; ++i) b[i] = *(const short8*)(B1b + boff[i]);
        if (Hs < nh) stageH(Hs);
        __builtin_amdgcn_sched_barrier(0);
        __builtin_amdgcn_s_barrier();
        asm volatile("s_waitcnt lgkmcnt(0)" ::: "memory");
        __builtin_amdgcn_sched_barrier(0);
        __builtin_amdgcn_s_setprio(1);
        #pragma unroll
        for (int mi = 0; mi < 4; ++mi)
            #pragma unroll
            for (int ni = 0; ni < 4; ++ni)
                acc[mi][ni] = MFMA16(a[mi], b[ni], acc[mi][ni]);
        __builtin_amdgcn_s_setprio(0);
        __builtin_amdgcn_sched_barrier(0);
        __builtin_amdgcn_s_barrier();

        // ---- phase 1: k[32:64), m4-7 ----
        #pragma unroll
        for (int i = 0; i < 4; ++i) a[i] = *(const short8*)(A1b + aoff[4 + i]);
        if (Hs + 1 < nh) stageH(Hs + 1);
        __builtin_amdgcn_sched_barrier(0);
        __builtin_amdgcn_s_barrier();
        asm volatile("s_waitcnt lgkmcnt(0)" ::: "memory");
        __builtin_amdgcn_sched_barrier(0);
        __builtin_amdgcn_s_setprio(1);
        #pragma unroll
        for (int mi = 0; mi < 4; ++mi)
            #pragma unroll
            for (int ni = 0; ni < 4; ++ni)
                acc[4 + mi][ni] = MFMA16(a[mi], b[ni], acc[4 + mi][ni]);
        __builtin_amdgcn_s_setprio(0);
        __builtin_amdgcn_sched_barrier(0);
        __builtin_amdgcn_s_barrier();

        // ---- phase 2: k[0:32), m0-3 ----
        #pragma unroll
        for (int i = 0; i < 4; ++i) a[i] = *(const short8*)(A0b + aoff[i]);
        #pragma unroll
        for (int i = 0; i < 4; ++i) b[i] = *(const short8*)(B0b + boff[i]);
        if (Hs + 2 < nh) stageH(Hs + 2);
        __builtin_amdgcn_sched_barrier(0);
        __builtin_amdgcn_s_barrier();
        asm volatile("s_waitcnt lgkmcnt(0)" ::: "memory");
        __builtin_amdgcn_sched_barrier(0);
        __builtin_amdgcn_s_setprio(1);
        #pragma unroll
        for (int mi = 0; mi < 4; ++mi)
            #pragma unroll
            for (int ni = 0; ni < 4; ++ni)
                acc[mi][ni] = MFMA16(a[mi], b[ni], acc[mi][ni]);
        __builtin_amdgcn_s_setprio(0);
        __builtin_amdgcn_sched_barrier(0);
        __builtin_amdgcn_s_barrier();

        // ---- phase 3: k[0:32), m4-7 ----
        #pragma unroll
        for (int i = 0; i < 4; ++i) a[i] = *(const short8*)(A0b + aoff[4 + i]);
        if (Hs + 3 < nh) stageH(Hs + 3);
        __builtin_amdgcn_sched_barrier(0);
        __builtin_amdgcn_s_barrier();
        asm volatile("s_waitcnt lgkmcnt(0)" ::: "memory");
        __builtin_amdgcn_sched_barrier(0);
        __builtin_amdgcn_s_setprio(1);
        #pragma unroll
        for (int mi = 0; mi < 4; ++mi)
            #pragma unroll
            for (int ni = 0; ni < 4; ++ni)
                acc[4 + mi][ni] = MFMA16(a[mi], b[ni], acc[4 + mi][ni]);
        __builtin_amdgcn_s_setprio(0);
        if (T < nt - 2) {
            asm volatile("s_waitcnt vmcnt(6)" ::: "memory");
        } else if (T == nt - 2) {
            asm volatile("s_waitcnt vmcnt(0)" ::: "memory");
        }
        __builtin_amdgcn_sched_barrier(0);
        __builtin_amdgcn_s_barrier();
    }

    if (VFUSE && n0 >= 2048) {
        // V region: write transposed to vt[(b*16+h)*64 + d][s], s = row index
        #pragma unroll
        for (int mi = 0; mi < 8; ++mi)
            #pragma unroll
            for (int ni = 0; ni < 4; ++ni) {
                int nn = n0 + wc * 64 + ni * 16 + lr;
                int h = (nn - 2048) >> 6, dd = (nn - 2048) & 63;
                int mm = m0 + wr * 128 + mi * 16 + lg * 4;
                int bb = mm >> 11, s = mm & 2047;
                short4v ov;
                #pragma unroll
                for (int rr = 0; rr < 4; ++rr) ov[rr] = f2bf(acc[mi][ni][rr]);
                *(short4v*)(vt + ((size_t)(bb * 16 + h) * 64 + dd) * 2048 + s) = ov;
            }
        return;
    }
    const float qs = (QSCALE && n0 < 1024) ? 1.4426950408889634f : 1.0f;
    #pragma unroll
    for (int mi = 0; mi < 8; ++mi)
        #pragma unroll
        for (int ni = 0; ni < 4; ++ni)
            #pragma unroll
            for (int rr = 0; rr < 4; ++rr) {
                int mm = m0 + wr * 128 + mi * 16 + lg * 4 + rr;
                int nn = n0 + wc * 64 + ni * 16 + lr;
                float v = acc[mi][ni][rr] * qs;
                if (OUT_BF16) ((short*)Cout)[(size_t)mm * N + nn] = f2bf(v);
                else ((float*)Cout)[(size_t)mm * N + nn] = v;
            }
}

// C[M,N] = A[M,K] * B[N,K]^T, bf16 in, fp32 accum (m97 structure) — for gemm2.
template <int OUT_BF16>
__global__ __launch_bounds__(256) void gemm_bt(const short* __restrict__ A,
                                               const short* __restrict__ B,
                                               void* __restrict__ Cout,
                                               int M, int N, int K) {
    __shared__ short sA[4096];
    __shared__ short sB[4096];
    const int t = threadIdx.x;
    const int l = t & 63, w = t >> 6;
    const int lr = l & 15, lg = l >> 4;
    const int m0 = blockIdx.y * 128, n0 = blockIdx.x * 128;
    const int wm = (w >> 1) * 64, wn = (w & 1) * 64;
    const int c0 = w * 64 + l, c1 = c0 + 256;
    const short* Ap0 = A + (size_t)(m0 + (c0 >> 2)) * K + (c0 & 3) * 8;
    const short* Ap1 = A + (size_t)(m0 + (c1 >> 2)) * K + (c1 & 3) * 8;
    const short* Bp0 = B + (size_t)(n0 + (c0 >> 2)) * K + (c0 & 3) * 8;
    const short* Bp1 = B + (size_t)(n0 + (c1 >> 2)) * K + (c1 & 3) * 8;
    short* lA0 = sA + w * 512;
    short* lA1 = sA + 2048 + w * 512;
    short* lB0 = sB + w * 512;
    short* lB1 = sB + 2048 + w * 512;
    f32x4 acc[4][4] = {};
    for (int k0 = 0; k0 < K; k0 += 32) {
        gload16(Ap0 + k0, lA0);
        gload16(Ap1 + k0, lA1);
        gload16(Bp0 + k0, lB0);
        gload16(Bp1 + k0, lB1);
        __syncthreads();
        short8 af[4], bfr[4];
        #pragma unroll
        for (int m = 0; m < 4; ++m) af[m] = *(const short8*)&sA[(wm + m * 16 + lr) * 32 + lg * 8];
        #pragma unroll
        for (int n = 0; n < 4; ++n) bfr[n] = *(const short8*)&sB[(wn + n * 16 + lr) * 32 + lg * 8];
        #pragma unroll
        for (int m = 0; m < 4; ++m)
            #pragma unroll
            for (int n = 0; n < 4; ++n)
                acc[m][n] = MFMA16(af[m], bfr[n], acc[m][n]);
        __syncthreads();
    }
    #pragma unroll
    for (int m = 0; m < 4; ++m)
        #pragma unroll
        for (int n = 0; n < 4; ++n)
            #pragma unroll
            for (int r = 0; r < 4; ++r) {
                int mm = m0 + wm + m * 16 + lg * 4 + r;
                int nn = n0 + wn + n * 16 + lr;
                float v = acc[m][n][r];
                if (OUT_BF16) ((short*)Cout)[(size_t)mm * N + nn] = f2bf(v);
                else ((float*)Cout)[(size_t)mm * N + nn] = v;
            }
}

// Flash attention, 32x32x16 MFMA, swapped-QK^T, exp2 domain, in-register P
// via cvt_pk + v_permlane32_swap (no sP LDS). 4 waves x 32 q-rows (q-tile 128),
// grid 512 (2/CU). K/V double-buffered, counted vmcnt, raw barriers.
__global__ __launch_bounds__(256, 2) void attn_kernel(const short* __restrict__ qkv,
                                                      const short* __restrict__ vt,
                                                      const int* __restrict__ amask,
                                                      const float* __restrict__ rel_bias,
                                                      short* __restrict__ xout) {
    __shared__ float tbl[376];     // bias*log2e for j-i in [-184,184]
    __shared__ short sK[2][4096];  // dbuf [key 64][dk 64], XOR-swizzled chunks
    __shared__ short sV[2][4096];  // dbuf [d 64][key 64], XOR-swizzled chunks
    __shared__ int mflags[32];     // per-64-key-tile all-nonzero flags
    const int t = threadIdx.x;     // 0..255
    const int l = t & 63, w = t >> 6;
    const int ql = l & 31, hi = l >> 5;
    const int qt = blockIdx.x, bh = blockIdx.y;
    const int b = bh >> 4, h = bh & 15;
    const int q0 = qt * 128 + w * 32;  // wave's 32 q-rows
    const float LOG2E = 1.4426950408889634f;

    if (t < 32) mflags[t] = ~0;
    for (int idx = t; idx < 369; idx += 256) {
        int d = idx - 184;
        int a = d < 0 ? -d : d;
        int fb = a < 8 ? a
                 : (a < 12 ? 8 : a < 16 ? 9 : a < 23 ? 10 : a < 32 ? 11
                    : a < 46 ? 12 : a < 64 ? 13 : a < 91 ? 14 : 15);
        int bk = (d > 0 ? 16 : 0) + fb;
        tbl[idx] = rel_bias[bk * 16 + h] * LOG2E;
    }
    const float rbp = rel_bias[31 * 16 + h] * LOG2E;  // all d >= 91
    const float rbn = rel_bias[15 * 16 + h] * LOG2E;  // all d <= -91

    // Q fragment (B operand of 32x32x16): n=q=ql, k = hi*8 + j within d-chunk dc
    short8 qf[4];
    #pragma unroll
    for (int dc = 0; dc < 4; ++dc)
        qf[dc] = *(const short8*)(qkv + (size_t)(b * 2048 + q0 + ql) * 3072 +
                                  h * 64 + dc * 16 + hi * 8);

    // my 8 mask values (keys t*8 .. t*8+7), all within 64-key tile t>>3
    const int4* mq = (const int4*)(amask + b * 2048 + t * 8);
    int4 ma0 = mq[0], ma1 = mq[1];

    // staging: thread t owns 16B chunks {t, t+256}; row=c>>3, colchunk=c&7;
    // global source col pre-swizzled by row&7 ((row+32)&7 == row&7).
    const int srow = t >> 3;  // 0..31
    const int scp = ((t & 7) ^ (srow & 7)) * 8;
    const short* kgp = qkv + (size_t)(b * 2048 + srow) * 3072 + 1024 + h * 64 + scp;
    const short* kgp2 = kgp + (size_t)32 * 3072;
    const short* vgp = vt + ((size_t)bh * 64 + srow) * 2048 + scp;
    const short* vgp2 = vgp + (size_t)32 * 2048;
    const int swq = ql & 7;

    __syncthreads();  // mflags/tbl visible; qf/mask vmem drained
    int mok = ma0.x & ma0.y & ma0.z & ma0.w & ma1.x & ma1.y & ma1.z & ma1.w;
    if (mok == 0) atomicAnd(&mflags[t >> 3], 0);
    __syncthreads();  // atomicAnd visible (raw barriers below don't drain lgkm)

    // prologue: stage tile 0 into buffer 0 (loads stay in flight)
    gload16(kgp, &sK[0][0] + t * 8);
    gload16(kgp2, &sK[0][0] + 2048 + t * 8);
    gload16(vgp, &sV[0][0] + t * 8);
    gload16(vgp2, &sV[0][0] + 2048 + t * 8);

    f32x16 o0 = {}, o1 = {};
    float mreg = -1e30f, lreg = 0.f;

    // pack 8 p-values (chunk of 16 keys) into the PV B-fragment via 2 permlane swaps
    auto mkfrag = [&](const f32x16& s, int base) -> short8 {
        unsigned w0 = cvt_pk_bf16(s[base + 0], s[base + 1]);
        unsigned w1 = cvt_pk_bf16(s[base + 2], s[base + 3]);
        unsigned w2 = cvt_pk_bf16(s[base + 4], s[base + 5]);
        unsigned w3 = cvt_pk_bf16(s[base + 6], s[base + 7]);
        asm volatile("v_permlane32_swap_b32 %0, %1" : "+v"(w0), "+v"(w2));
        asm volatile("v_permlane32_swap_b32 %0, %1" : "+v"(w1), "+v"(w3));
        union { unsigned u[4]; short8 s8; } r;
        r.u[0] = w0; r.u[1] = w1; r.u[2] = w2; r.u[3] = w3;
        return r.s8;
    };

    for (int kt = 0; kt < 2048; kt += 64) {
        const int cur = (kt >> 6) & 1;
        if (kt + 64 < 2048) {
            gload16(kgp + (size_t)(kt + 64) * 3072, &sK[cur ^ 1][0] + t * 8);
            gload16(kgp2 + (size_t)(kt + 64) * 3072, &sK[cur ^ 1][0] + 2048 + t * 8);
            gload16(vgp + kt + 64, &sV[cur ^ 1][0] + t * 8);
            gload16(vgp2 + kt + 64, &sV[cur ^ 1][0] + 2048 + t * 8);
            asm volatile("s_waitcnt vmcnt(4)" ::: "memory");  // tile-cur landed
        } else {
            asm volatile("s_waitcnt vmcnt(0)" ::: "memory");
        }
        __builtin_amdgcn_sched_barrier(0);
        __builtin_amdgcn_s_barrier();
        __builtin_amdgcn_sched_barrier(0);

        const short* kb = &sK[cur][0];
        const short* vb = &sV[cur][0];

        // S^T = K * Q^T (32x32x16): lane holds q=q0+ql; keys per reg:
        // key = (reg&3) + 8*(reg>>2) + 4*hi (+32 for s1)
        f32x16 s0 = {}, s1 = {};
        #pragma unroll
        for (int dc = 0; dc < 4; ++dc) {
            short8 kf0 = *(const short8*)&kb[ql * 64 + (((dc * 2 + hi) ^ swq) * 8)];
            short8 kf1 = *(const short8*)&kb[(32 + ql) * 64 + (((dc * 2 + hi) ^ swq) * 8)];
            s0 = MFMA32(kf0, qf[dc], s0);
            s1 = MFMA32(kf1, qf[dc], s1);
        }

        // bias (log2 domain)
        float cb;
        if (kt >= q0 + 122) {
            cb = rbp;
        } else if (kt + 63 <= q0 - 91) {
            cb = rbn;
        } else {
            cb = 0.f;
            const int ib = kt - q0 - ql + 184;
            #pragma unroll
            for (int reg = 0; reg < 16; ++reg) {
                const int row = (reg & 3) + 8 * (reg >> 2) + 4 * hi;
                s0[reg] += tbl[ib + row];
                s1[reg] += tbl[ib + 32 + row];
            }
        }

        // lane-local max over 32 scores (tree)
        float m0 = fmaxf(s0[0], s0[1]), m1 = fmaxf(s0[2], s0[3]);
        float m2 = fmaxf(s0[4], s0[5]), m3 = fmaxf(s0[6], s0[7]);
        float m4 = fmaxf(s0[8], s0[9]), m5 = fmaxf(s0[10], s0[11]);
        float m6 = fmaxf(s0[12], s0[13]), m7 = fmaxf(s0[14], s0[15]);
        float n0_ = fmaxf(s1[0], s1[1]), n1 = fmaxf(s1[2], s1[3]);
        float n2 = fmaxf(s1[4], s1[5]), n3 = fmaxf(s1[6], s1[7]);
        float n4 = fmaxf(s1[8], s1[9]), n5 = fmaxf(s1[10], s1[11]);
        float n6 = fmaxf(s1[12], s1[13]), n7 = fmaxf(s1[14], s1[15]);
        float lmax = fmaxf(
            fmaxf(fmaxf(fmaxf(m0, m1), fmaxf(m2, m3)), fmaxf(fmaxf(m4, m5), fmaxf(m6, m7))),
            fmaxf(fmaxf(fmaxf(n0_, n1), fmaxf(n2, n3)), fmaxf(fmaxf(n4, n5), fmaxf(n6, n7))));
        if (__any(lmax > mreg - cb + 11.5f)) {
            float rm = fmaxf(lmax, __shfl_xor(lmax, 32));
            float mnew = fmaxf(mreg, rm + cb);
            float alpha = fexp2(mreg - mnew);
            lreg *= alpha;
            #pragma unroll
            for (int reg = 0; reg < 16; ++reg) {
                o0[reg] *= alpha;
                o1[reg] *= alpha;
            }
            mreg = mnew;
        }
        const float madj = mreg - cb;
        const int tok = mflags[kt >> 6];
        #pragma unroll
        for (int reg = 0; reg < 16; ++reg) {
            s0[reg] = fexp2(s0[reg] - madj);
            s1[reg] = fexp2(s1[reg] - madj);
        }
        if (!tok) {  // exact masking slow path (never taken for all-ones mask)
            #pragma unroll
            for (int reg = 0; reg < 16; ++reg) {
                const int row = (reg & 3) + 8 * (reg >> 2) + 4 * hi;
                s0[reg] = amask[b * 2048 + kt + row] ? s0[reg] : 0.f;
                s1[reg] = amask[b * 2048 + kt + 32 + row] ? s1[reg] : 0.f;
            }
        }
        float rs = 0.f;
        #pragma unroll
        for (int reg = 0; reg < 16; ++reg) rs += s0[reg] + s1[reg];
        lreg += rs;

        // P fragments in-register (no LDS): kc = key chunk of 16
        short8 pf0 = mkfrag(s0, 0);
        short8 pf1 = mkfrag(s0, 8);
        short8 pf2 = mkfrag(s1, 0);
        short8 pf3 = mkfrag(s1, 8);

        // O^T += V^T * P^T (32x32x16): A=vf rows d, B=pf
        #pragma unroll
        for (int kc = 0; kc < 4; ++kc) {
            short8 pf = (kc == 0) ? pf0 : (kc == 1) ? pf1 : (kc == 2) ? pf2 : pf3;
            short8 vf0 = *(const short8*)&vb[ql * 64 + (((kc * 2 + hi) ^ swq) * 8)];
            short8 vf1 = *(const short8*)&vb[(32 + ql) * 64 + (((kc * 2 + hi) ^ swq) * 8)];
            o0 = MFMA32(vf0, pf, o0);
            o1 = MFMA32(vf1, pf, o1);
        }
        __builtin_amdgcn_sched_barrier(0);
        __builtin_amdgcn_s_barrier();  // all waves done reading buf[cur]
        __builtin_amdgcn_sched_barrier(0);
    }

    float lsum = lreg + __shfl_xor(lreg, 32);
    const float inv = 1.0f / lsum;
    // write: q = q0+ql; o0 rows d = (reg&3)+8*(reg>>2)+4*hi, o1 at d+32
    short* xrow = xout + (size_t)(b * 2048 + q0 + ql) * 1024 + h * 64;
    #pragma unroll
    for (int g = 0; g < 4; ++g) {
        short4v ov0, ov1;
        #pragma unroll
        for (int r = 0; r < 4; ++r) {
            ov0[r] = f2bf(o0[g * 4 + r] * inv);
            ov1[r] = f2bf(o1[g * 4 + r] * inv);
        }
        *(short4v*)(xrow + g * 8 + 4 * hi) = ov0;
        *(short4v*)(xrow + 32 + g * 8 + 4 * hi) = ov1;
    }
}

extern "C" void kernel_launch(void* const* d_in, const int* in_sizes, int n_in,
                              void* d_out, int out_size, void* d_ws, size_t ws_size,
                              hipStream_t stream) {
    const float* hidden = (const float*)d_in[0];
    const int* amask = (const int*)d_in[1];
    const float* w_qkv = (const float*)d_in[2];
    const float* rel_bias = (const float*)d_in[3];
    const float* w_o = (const float*)d_in[4];
    if (ws_size < 58720256) return;
    char* ws = (char*)d_ws;
    short* hidden_bf = (short*)(ws + 0);
    short* wqkv_bf   = (short*)(ws + 8388608);
    short* wo_bf     = (short*)(ws + 14680064);
    short* qkv       = (short*)(ws + 16777216);
    short* vt        = (short*)(ws + 41943040);
    short* xbuf      = (short*)(ws + 50331648);

    cast_all<<<4096, 256, 0, stream>>>(hidden, w_qkv, w_o, hidden_bf, wqkv_bf, wo_bf);
    gemm8p<1, 1, 1><<<dim3(12, 16), 512, 0, stream>>>(hidden_bf, wqkv_bf, qkv, vt, 4096, 3072, 1024);
    attn_kernel<<<dim3(16, 32), 256, 0, stream>>>(qkv, vt, amask, rel_bias, xbuf);
    gemm_bt<0><<<dim3(8, 32), 256, 0, stream>>>(xbuf, wo_bf, d_out, 4096, 1024, 1024);
}

// Round 20
// 131.816 us; speedup vs baseline: 1.0203x; 1.0203x over previous
//
#include <hip/hip_runtime.h>
#include <stdint.h>

typedef __attribute__((ext_vector_type(4))) float f32x4;
typedef __attribute__((ext_vector_type(8))) short short8;
typedef __attribute__((ext_vector_type(4))) short short4v;
typedef __attribute__((ext_vector_type(2))) unsigned uint2v;

__device__ __forceinline__ short f2bf(float f) {
    union { float f; unsigned u; } x; x.f = f;
    return (short)((x.u + 0x7fffu + ((x.u >> 16) & 1u)) >> 16);
}

__device__ __forceinline__ unsigned cvt_pk_bf16(float lo, float hi) {
    unsigned r;
    asm("v_cvt_pk_bf16_f32 %0, %1, %2" : "=v"(r) : "v"(lo), "v"(hi));
    return r;
}

__device__ __forceinline__ float fexp2(float x) {
#if __has_builtin(__builtin_amdgcn_exp2f)
    return __builtin_amdgcn_exp2f(x);
#else
    return exp2f(x);
#endif
}

#define MFMA16(a, b, c) __builtin_amdgcn_mfma_f32_16x16x32_bf16((a), (b), (c), 0, 0, 0)

__device__ __forceinline__ void gload16(const void* g, void* l) {
    __builtin_amdgcn_global_load_lds((const __attribute__((address_space(1))) void*)g,
                                     (__attribute__((address_space(3))) void*)l, 16, 0, 0);
}

// all three f32->bf16 casts in one launch
__global__ __launch_bounds__(256) void cast_all(const float* __restrict__ h,
                                                const float* __restrict__ wq,
                                                const float* __restrict__ wo,
                                                short* __restrict__ hb,
                                                short* __restrict__ wqb,
                                                short* __restrict__ wob) {
    int i = blockIdx.x * 256 + threadIdx.x;  // 1048576 chunks of 8
    const float* s;
    short* d;
    int j;
    if (i < 524288) { s = h; d = hb; j = i; }
    else if (i < 917504) { s = wq; d = wqb; j = i - 524288; }
    else { s = wo; d = wob; j = i - 917504; }
    float4 a = ((const float4*)s)[j * 2];
    float4 b = ((const float4*)s)[j * 2 + 1];
    short8 o;
    o[0] = f2bf(a.x); o[1] = f2bf(a.y); o[2] = f2bf(a.z); o[3] = f2bf(a.w);
    o[4] = f2bf(b.x); o[5] = f2bf(b.y); o[6] = f2bf(b.z); o[7] = f2bf(b.w);
    ((short8*)d)[j] = o;
}

// ------------------- 8-phase 256x256 GEMM (C = A * B^T) -------------------
// QSCALE: scale cols [0,1024) by log2e. VFUSE: for n0>=2048 (V region) write
// transposed into vt[bh][d][s] instead of C (fuses the old transpose_v pass).
template <int OUT_BF16, int QSCALE, int VFUSE>
__global__ __launch_bounds__(512, 2) void gemm8p(const short* __restrict__ A,
                                                 const short* __restrict__ B,
                                                 void* __restrict__ Cout,
                                                 short* __restrict__ vt,
                                                 int M, int N, int K) {
    __shared__ short lds[2][4][8192];  // 128 KB
    const int t = threadIdx.x;
    const int l = t & 63, w = t >> 6;
    const int lr = l & 15, lg = l >> 4;
    const int wr = w >> 2, wc = w & 3;
    const int m0 = blockIdx.y * 256, n0 = blockIdx.x * 256;
    const int nt = K >> 6, nh = nt << 2;

    const int sr0 = t >> 2;
    const int scc = ((t & 3) ^ ((sr0 >> 1) & 3)) * 8;
    const short* As0 = A + (size_t)(m0 + sr0) * K + scc;
    const short* As1 = A + (size_t)(m0 + sr0 + 128) * K + scc;
    const short* Bs0 = B + (size_t)(n0 + sr0) * K + scc;
    const short* Bs1 = B + (size_t)(n0 + sr0 + 128) * K + scc;
    short* ldsb = &lds[0][0][0];

    auto stageH = [&](int H) {
        int Tp = H >> 2, pos = H & 3;
        int kb = Tp * 64 + ((pos <= 1) ? 32 : 0);
        short* dst = ldsb + ((Tp & 1) * 4 + pos) * 8192 + t * 8;
        if (pos & 1) {
            gload16(As0 + kb, dst);
            gload16(As1 + kb, dst + 4096);
        } else {
            gload16(Bs0 + kb, dst);
            gload16(Bs1 + kb, dst + 4096);
        }
    };

    int aoff[8], boff[4];
    #pragma unroll
    for (int mi = 0; mi < 8; ++mi) {
        int row = wr * 128 + mi * 16 + lr;
        aoff[mi] = row * 32 + (lg ^ ((row >> 1) & 3)) * 8;
    }
    #pragma unroll
    for (int ni = 0; ni < 4; ++ni) {
        int row = wc * 64 + ni * 16 + lr;
        boff[ni] = row * 32 + (lg ^ ((row >> 1) & 3)) * 8;
    }

    f32x4 acc[8][4] = {};

    for (int H = 0; H < 7; ++H) stageH(H);
    asm volatile("s_waitcnt vmcnt(6)" ::: "memory");
    __builtin_amdgcn_s_barrier();

    for (int T = 0; T < nt; ++T) {
        const short* rbase = ldsb + (T & 1) * 32768;
        const short* B1b = rbase;
        const short* A1b = rbase + 8192;
        const short* B0b = rbase + 16384;
        const short* A0b = rbase + 24576;
        const int Hs = (T << 2) + 7;
        short8 a[4], b[4];

        // ---- phase 0: k[32:64), m0-3 ----
        #pragma unroll
        for (int i = 0; i < 4; ++i) a[i] = *(const short8*)(A1b + aoff[i]);
        #pragma unroll
        for (int i = 0; i < 4; ++i) b[i] = *(const short8*)(B1b + boff[i]);
        if (Hs < nh) stageH(Hs);
        __builtin_amdgcn_sched_barrier(0);
        __builtin_amdgcn_s_barrier();
        asm volatile("s_waitcnt lgkmcnt(0)" ::: "memory");
        __builtin_amdgcn_sched_barrier(0);
        __builtin_amdgcn_s_setprio(1);
        #pragma unroll
        for (int mi = 0; mi < 4; ++mi)
            #pragma unroll
            for (int ni = 0; ni < 4; ++ni)
                acc[mi][ni] = MFMA16(a[mi], b[ni], acc[mi][ni]);
        __builtin_amdgcn_s_setprio(0);
        __builtin_amdgcn_sched_barrier(0);
        __builtin_amdgcn_s_barrier();

        // ---- phase 1: k[32:64), m4-7 ----
        #pragma unroll
        for (int i = 0; i < 4; ++i) a[i] = *(const short8*)(A1b + aoff[4 + i]);
        if (Hs + 1 < nh) stageH(Hs + 1);
        __builtin_amdgcn_sched_barrier(0);
        __builtin_amdgcn_s_barrier();
        asm volatile("s_waitcnt lgkmcnt(0)" ::: "memory");
        __builtin_amdgcn_sched_barrier(0);
        __builtin_amdgcn_s_setprio(1);
        #pragma unroll
        for (int mi = 0; mi < 4; ++mi)
            #pragma unroll
            for (int ni = 0; ni < 4; ++ni)
                acc[4 + mi][ni] = MFMA16(a[mi], b[ni], acc[4 + mi][ni]);
        __builtin_amdgcn_s_setprio(0);
        __builtin_amdgcn_sched_barrier(0);
        __builtin_amdgcn_s_barrier();

        // ---- phase 2: k[0:32), m0-3 ----
        #pragma unroll
        for (int i = 0; i < 4; ++i) a[i] = *(const short8*)(A0b + aoff[i]);
        #pragma unroll
        for (int i = 0; i < 4; ++i) b[i] = *(const short8*)(B0b + boff[i]);
        if (Hs + 2 < nh) stageH(Hs + 2);
        __builtin_amdgcn_sched_barrier(0);
        __builtin_amdgcn_s_barrier();
        asm volatile("s_waitcnt lgkmcnt(0)" ::: "memory");
        __builtin_amdgcn_sched_barrier(0);
        __builtin_amdgcn_s_setprio(1);
        #pragma unroll
        for (int mi = 0; mi < 4; ++mi)
            #pragma unroll
            for (int ni = 0; ni < 4; ++ni)
                acc[mi][ni] = MFMA16(a[mi], b[ni], acc[mi][ni]);
        __builtin_amdgcn_s_setprio(0);
        __builtin_amdgcn_sched_barrier(0);
        __builtin_amdgcn_s_barrier();

        // ---- phase 3: k[0:32), m4-7 ----
        #pragma unroll
        for (int i = 0; i < 4; ++i) a[i] = *(const short8*)(A0b + aoff[4 + i]);
        if (Hs + 3 < nh) stageH(Hs + 3);
        __builtin_amdgcn_sched_barrier(0);
        __builtin_amdgcn_s_barrier();
        asm volatile("s_waitcnt lgkmcnt(0)" ::: "memory");
        __builtin_amdgcn_sched_barrier(0);
        __builtin_amdgcn_s_setprio(1);
        #pragma unroll
        for (int mi = 0; mi < 4; ++mi)
            #pragma unroll
            for (int ni = 0; ni < 4; ++ni)
                acc[4 + mi][ni] = MFMA16(a[mi], b[ni], acc[4 + mi][ni]);
        __builtin_amdgcn_s_setprio(0);
        if (T < nt - 2) {
            asm volatile("s_waitcnt vmcnt(6)" ::: "memory");
        } else if (T == nt - 2) {
            asm volatile("s_waitcnt vmcnt(0)" ::: "memory");
        }
        __builtin_amdgcn_sched_barrier(0);
        __builtin_amdgcn_s_barrier();
    }

    if (VFUSE && n0 >= 2048) {
        // V region: write transposed to vt[(b*16+h)*64 + d][s], s = row index
        #pragma unroll
        for (int mi = 0; mi < 8; ++mi)
            #pragma unroll
            for (int ni = 0; ni < 4; ++ni) {
                int nn = n0 + wc * 64 + ni * 16 + lr;
                int h = (nn - 2048) >> 6, dd = (nn - 2048) & 63;
                int mm = m0 + wr * 128 + mi * 16 + lg * 4;
                int bb = mm >> 11, s = mm & 2047;
                short4v ov;
                #pragma unroll
                for (int rr = 0; rr < 4; ++rr) ov[rr] = f2bf(acc[mi][ni][rr]);
                *(short4v*)(vt + ((size_t)(bb * 16 + h) * 64 + dd) * 2048 + s) = ov;
            }
        return;
    }
    const float qs = (QSCALE && n0 < 1024) ? 1.4426950408889634f : 1.0f;
    #pragma unroll
    for (int mi = 0; mi < 8; ++mi)
        #pragma unroll
        for (int ni = 0; ni < 4; ++ni)
            #pragma unroll
            for (int rr = 0; rr < 4; ++rr) {
                int mm = m0 + wr * 128 + mi * 16 + lg * 4 + rr;
                int nn = n0 + wc * 64 + ni * 16 + lr;
                float v = acc[mi][ni][rr] * qs;
                if (OUT_BF16) ((short*)Cout)[(size_t)mm * N + nn] = f2bf(v);
                else ((float*)Cout)[(size_t)mm * N + nn] = v;
            }
}

// C[M,N] = A[M,K] * B[N,K]^T, bf16 in, fp32 accum (m97 structure) — for gemm2.
template <int OUT_BF16>
__global__ __launch_bounds__(256) void gemm_bt(const short* __restrict__ A,
                                               const short* __restrict__ B,
                                               void* __restrict__ Cout,
                                               int M, int N, int K) {
    __shared__ short sA[4096];
    __shared__ short sB[4096];
    const int t = threadIdx.x;
    const int l = t & 63, w = t >> 6;
    const int lr = l & 15, lg = l >> 4;
    const int m0 = blockIdx.y * 128, n0 = blockIdx.x * 128;
    const int wm = (w >> 1) * 64, wn = (w & 1) * 64;
    const int c0 = w * 64 + l, c1 = c0 + 256;
    const short* Ap0 = A + (size_t)(m0 + (c0 >> 2)) * K + (c0 & 3) * 8;
    const short* Ap1 = A + (size_t)(m0 + (c1 >> 2)) * K + (c1 & 3) * 8;
    const short* Bp0 = B + (size_t)(n0 + (c0 >> 2)) * K + (c0 & 3) * 8;
    const short* Bp1 = B + (size_t)(n0 + (c1 >> 2)) * K + (c1 & 3) * 8;
    short* lA0 = sA + w * 512;
    short* lA1 = sA + 2048 + w * 512;
    short* lB0 = sB + w * 512;
    short* lB1 = sB + 2048 + w * 512;
    f32x4 acc[4][4] = {};
    for (int k0 = 0; k0 < K; k0 += 32) {
        gload16(Ap0 + k0, lA0);
        gload16(Ap1 + k0, lA1);
        gload16(Bp0 + k0, lB0);
        gload16(Bp1 + k0, lB1);
        __syncthreads();
        short8 af[4], bfr[4];
        #pragma unroll
        for (int m = 0; m < 4; ++m) af[m] = *(const short8*)&sA[(wm + m * 16 + lr) * 32 + lg * 8];
        #pragma unroll
        for (int n = 0; n < 4; ++n) bfr[n] = *(const short8*)&sB[(wn + n * 16 + lr) * 32 + lg * 8];
        #pragma unroll
        for (int m = 0; m < 4; ++m)
            #pragma unroll
            for (int n = 0; n < 4; ++n)
                acc[m][n] = MFMA16(af[m], bfr[n], acc[m][n]);
        __syncthreads();
    }
    #pragma unroll
    for (int m = 0; m < 4; ++m)
        #pragma unroll
        for (int n = 0; n < 4; ++n)
            #pragma unroll
            for (int r = 0; r < 4; ++r) {
                int mm = m0 + wm + m * 16 + lg * 4 + r;
                int nn = n0 + wn + n * 16 + lr;
                float v = acc[m][n][r];
                if (OUT_BF16) ((short*)Cout)[(size_t)mm * N + nn] = f2bf(v);
                else ((float*)Cout)[(size_t)mm * N + nn] = v;
            }
}

// Flash attention, swapped-QK^T, exp2 domain. 8 waves x 16 q-rows (q-tile 128),
// single K/V LDS buffer, grid 512 (2/CU, 16 waves/CU). R16 structure exactly,
// plus XCD-chunked block swizzle: each XCD owns 4 contiguous bh (K/V L2-resident).
__global__ __launch_bounds__(512, 4) void attn_kernel(const short* __restrict__ qkv,
                                                      const short* __restrict__ vt,
                                                      const int* __restrict__ amask,
                                                      const float* __restrict__ rel_bias,
                                                      short* __restrict__ xout) {
    __shared__ float tbl[340];       // bias*log2e for j-i in [-168,168]
    __shared__ short sK[4096];       // [key 64][dk 64], XOR-swizzled chunks
    __shared__ short sV[4096];       // [d 64][key 64], XOR-swizzled chunks
    __shared__ short sP[8][16][72];  // per-wave P^T
    __shared__ int mflags[32];       // per-64-key-tile all-nonzero flags
    const int t = threadIdx.x;       // 0..511
    const int l = t & 63, w = t >> 6;
    const int lr = l & 15, lg = l >> 4;
    // XCD-chunked bijective swizzle: 512 wgs = 8 XCDs x 64; each XCD gets
    // bh in [xcd*4, xcd*4+4) for all 16 q-tiles (2 MB K/V per XCD < 4 MB L2).
    const int wg = blockIdx.y * 16 + blockIdx.x;
    const int swz = (wg & 7) * 64 + (wg >> 3);
    const int qt = swz & 15, bh = swz >> 4;
    const int b = bh >> 4, h = bh & 15;
    const int q0 = qt * 128 + w * 16;
    const float LOG2E = 1.4426950408889634f;

    if (t < 32) mflags[t] = ~0;
    if (t < 337) {
        int idx = t;
        int d = idx - 168;
        int a = d < 0 ? -d : d;
        int fb = a < 8 ? a
                 : (a < 12 ? 8 : a < 16 ? 9 : a < 23 ? 10 : a < 32 ? 11
                    : a < 46 ? 12 : a < 64 ? 13 : a < 91 ? 14 : 15);
        int bk = (d > 0 ? 16 : 0) + fb;
        tbl[idx] = rel_bias[bk * 16 + h] * LOG2E;
    }
    const float rbp = rel_bias[31 * 16 + h] * LOG2E;  // d >= 91
    const float rbn = rel_bias[15 * 16 + h] * LOG2E;  // d <= -91

    short8 qf[2];
    #pragma unroll
    for (int ds = 0; ds < 2; ++ds)
        qf[ds] = *(const short8*)(qkv + (size_t)(b * 2048 + q0 + lr) * 3072 + h * 64 + ds * 32 + lg * 8);

    // my 4 mask values (keys t*4 .. t*4+3), all within key-tile t>>4
    const int4 ma = ((const int4*)(amask + b * 2048))[t];

    // staging: thread t owns 16B chunk t of sK and sV; row = t>>3 (0..63),
    // source col pre-swizzled by row&7 so swizzled reads see linear data.
    const int srow = t >> 3;
    const int scp = ((t & 7) ^ (srow & 7)) * 8;
    const short* kgp = qkv + (size_t)(b * 2048 + srow) * 3072 + 1024 + h * 64 + scp;
    const short* vgp = vt + ((size_t)bh * 64 + srow) * 2048 + scp;
    short* dK = sK + t * 8;
    short* dV = sV + t * 8;
    const int sw8 = (lr & 7) * 8;
    const int ibb = -q0 + lg * 4 - lr + 168;

    __syncthreads();  // mflags init visible
    int mok = ma.x & ma.y & ma.z & ma.w;
    if (mok == 0) atomicAnd(&mflags[t >> 4], 0);

    f32x4 o[4] = {};
    float mreg = -1e30f, lreg = 0.f;

    for (int kt = 0; kt < 2048; kt += 64) {
        gload16(kgp + (size_t)kt * 3072, dK);
        gload16(vgp + kt, dV);
        __syncthreads();  // stage drained (+ atomicAnd visible on first iter)

        // S^T = K * Q^T : lane holds q = q0+lr, keys kt + ct*16 + lg*4 + r
        f32x4 pe[4];
        #pragma unroll
        for (int ct = 0; ct < 4; ++ct) {
            f32x4 z = {};
            #pragma unroll
            for (int ds = 0; ds < 2; ++ds) {
                short8 kf = *(const short8*)&sK[(ct * 16 + lr) * 64 + ((ds * 32 + lg * 8) ^ sw8)];
                z = MFMA16(kf, qf[ds], z);
            }
            pe[ct] = z;
        }

        // bias (log2 domain)
        float cb;
        if (kt >= q0 + 106) {
            cb = rbp;
        } else if (kt + 63 <= q0 - 91) {
            cb = rbn;
        } else {
            cb = 0.f;
            const int ib = kt + ibb;
            #pragma unroll
            for (int ct = 0; ct < 4; ++ct)
                #pragma unroll
                for (int r = 0; r < 4; ++r)
                    pe[ct][r] += tbl[ib + ct * 16 + r];
        }

        // lane-local max (tree, max3-fusable)
        float t0 = fmaxf(fmaxf(pe[0][0], pe[0][1]), fmaxf(pe[0][2], pe[0][3]));
        float t1 = fmaxf(fmaxf(pe[1][0], pe[1][1]), fmaxf(pe[1][2], pe[1][3]));
        float t2 = fmaxf(fmaxf(pe[2][0], pe[2][1]), fmaxf(pe[2][2], pe[2][3]));
        float t3 = fmaxf(fmaxf(pe[3][0], pe[3][1]), fmaxf(pe[3][2], pe[3][3]));
        float lmax = fmaxf(fmaxf(t0, t1), fmaxf(t2, t3));
        if (__any(lmax > mreg - cb + 11.5f)) {
            float rm = fmaxf(lmax, __shfl_xor(lmax, 16));
            rm = fmaxf(rm, __shfl_xor(rm, 32));
            float mnew = fmaxf(mreg, rm + cb);
            float alpha = fexp2(mreg - mnew);
            lreg *= alpha;
            #pragma unroll
            for (int dt = 0; dt < 4; ++dt)
                #pragma unroll
                for (int r = 0; r < 4; ++r)
                    o[dt][r] *= alpha;
            mreg = mnew;
        }
        const float madj = mreg - cb;
        const int tok = mflags[kt >> 6];
        float rs = 0.f;
        if (tok) {
            #pragma unroll
            for (int ct = 0; ct < 4; ++ct) {
                float p[4];
                #pragma unroll
                for (int r = 0; r < 4; ++r) {
                    float pv = fexp2(pe[ct][r] - madj);
                    p[r] = pv;
                    rs += pv;
                }
                uint2v pk;
                pk[0] = cvt_pk_bf16(p[0], p[1]);
                pk[1] = cvt_pk_bf16(p[2], p[3]);
                *(uint2v*)&sP[w][lr][ct * 16 + lg * 4] = pk;
            }
        } else {
            const int4* mp = (const int4*)(amask + b * 2048 + kt);
            #pragma unroll
            for (int ct = 0; ct < 4; ++ct) {
                int4 cm = mp[ct * 4 + lg];
                float p[4];
                #pragma unroll
                for (int r = 0; r < 4; ++r) {
                    float pv = fexp2(pe[ct][r] - madj);
                    pv = ((const int*)&cm)[r] ? pv : 0.f;
                    p[r] = pv;
                    rs += pv;
                }
                uint2v pk;
                pk[0] = cvt_pk_bf16(p[0], p[1]);
                pk[1] = cvt_pk_bf16(p[2], p[3]);
                *(uint2v*)&sP[w][lr][ct * 16 + lg * 4] = pk;
            }
        }
        lreg += rs;

        // O^T += V^T * P^T
        #pragma unroll
        for (int kk = 0; kk < 2; ++kk) {
            short8 pf = *(const short8*)&sP[w][lr][kk * 32 + lg * 8];
            #pragma unroll
            for (int dt = 0; dt < 4; ++dt) {
                short8 vf = *(const short8*)&sV[(dt * 16 + lr) * 64 + ((kk * 32 + lg * 8) ^ sw8)];
                o[dt] = MFMA16(vf, pf, o[dt]);
            }
        }
        __syncthreads();  // all waves done with sK/sV before next stage
    }

    float lsum = lreg + __shfl_xor(lreg, 16);
    lsum += __shfl_xor(lsum, 32);
    const float inv = 1.0f / lsum;
    #pragma unroll
    for (int dt = 0; dt < 4; ++dt) {
        short4v ov;
        #pragma unroll
        for (int r = 0; r < 4; ++r) ov[r] = f2bf(o[dt][r] * inv);
        *(short4v*)(xout + (size_t)(b * 2048 + q0 + lr) * 1024 + h * 64 + dt * 16 + lg * 4) = ov;
    }
}

extern "C" void kernel_launch(void* const* d_in, const int* in_sizes, int n_in,
                              void* d_out, int out_size, void* d_ws, size_t ws_size,
                              hipStream_t stream) {
    const float* hidden = (const float*)d_in[0];
    const int* amask = (const int*)d_in[1];
    const float* w_qkv = (const float*)d_in[2];
    const float* rel_bias = (const float*)d_in[3];
    const float* w_o = (const float*)d_in[4];
    if (ws_size < 58720256) return;
    char* ws = (char*)d_ws;
    short* hidden_bf = (short*)(ws + 0);
    short* wqkv_bf   = (short*)(ws + 8388608);
    short* wo_bf     = (short*)(ws + 14680064);
    short* qkv       = (short*)(ws + 16777216);
    short* vt        = (short*)(ws + 41943040);
    short* xbuf      = (short*)(ws + 50331648);

    cast_all<<<4096, 256, 0, stream>>>(hidden, w_qkv, w_o, hidden_bf, wqkv_bf, wo_bf);
    gemm8p<1, 1, 1><<<dim3(12, 16), 512, 0, stream>>>(hidden_bf, wqkv_bf, qkv, vt, 4096, 3072, 1024);
    attn_kernel<<<dim3(16, 32), 512, 0, stream>>>(qkv, vt, amask, rel_bias, xbuf);
    gemm_bt<0><<<dim3(8, 32), 256, 0, stream>>>(xbuf, wo_bf, d_out, 4096, 1024, 1024);
}

// Round 21
// 128.905 us; speedup vs baseline: 1.0433x; 1.0226x over previous
//
#include <hip/hip_runtime.h>
#include <stdint.h>

typedef __attribute__((ext_vector_type(4))) float f32x4;
typedef __attribute__((ext_vector_type(8))) short short8;
typedef __attribute__((ext_vector_type(4))) short short4v;
typedef __attribute__((ext_vector_type(2))) unsigned uint2v;

__device__ __forceinline__ short f2bf(float f) {
    union { float f; unsigned u; } x; x.f = f;
    return (short)((x.u + 0x7fffu + ((x.u >> 16) & 1u)) >> 16);
}

__device__ __forceinline__ unsigned cvt_pk_bf16(float lo, float hi) {
    unsigned r;
    asm("v_cvt_pk_bf16_f32 %0, %1, %2" : "=v"(r) : "v"(lo), "v"(hi));
    return r;
}

__device__ __forceinline__ float fexp2(float x) {
#if __has_builtin(__builtin_amdgcn_exp2f)
    return __builtin_amdgcn_exp2f(x);
#else
    return exp2f(x);
#endif
}

#define MFMA16(a, b, c) __builtin_amdgcn_mfma_f32_16x16x32_bf16((a), (b), (c), 0, 0, 0)

__device__ __forceinline__ void gload16(const void* g, void* l) {
    __builtin_amdgcn_global_load_lds((const __attribute__((address_space(1))) void*)g,
                                     (__attribute__((address_space(3))) void*)l, 16, 0, 0);
}

// all three f32->bf16 casts in one launch
__global__ __launch_bounds__(256) void cast_all(const float* __restrict__ h,
                                                const float* __restrict__ wq,
                                                const float* __restrict__ wo,
                                                short* __restrict__ hb,
                                                short* __restrict__ wqb,
                                                short* __restrict__ wob) {
    int i = blockIdx.x * 256 + threadIdx.x;  // 1048576 chunks of 8
    const float* s;
    short* d;
    int j;
    if (i < 524288) { s = h; d = hb; j = i; }
    else if (i < 917504) { s = wq; d = wqb; j = i - 524288; }
    else { s = wo; d = wob; j = i - 917504; }
    float4 a = ((const float4*)s)[j * 2];
    float4 b = ((const float4*)s)[j * 2 + 1];
    short8 o;
    o[0] = f2bf(a.x); o[1] = f2bf(a.y); o[2] = f2bf(a.z); o[3] = f2bf(a.w);
    o[4] = f2bf(b.x); o[5] = f2bf(b.y); o[6] = f2bf(b.z); o[7] = f2bf(b.w);
    ((short8*)d)[j] = o;
}

// ------------------- 8-phase 256x256 GEMM (C = A * B^T) -------------------
// QSCALE: scale cols [0,1024) by log2e. VFUSE: for n0>=2048 (V region) write
// transposed into vt[bh][d][s] instead of C. XCD-chunked block swizzle:
// grid must be 12x16 (192 blocks); each XCD owns a 4Mx6N region (~5 MB set).
template <int OUT_BF16, int QSCALE, int VFUSE>
__global__ __launch_bounds__(512, 2) void gemm8p(const short* __restrict__ A,
                                                 const short* __restrict__ B,
                                                 void* __restrict__ Cout,
                                                 short* __restrict__ vt,
                                                 int M, int N, int K) {
    __shared__ short lds[2][4][8192];  // 128 KB
    const int t = threadIdx.x;
    const int l = t & 63, w = t >> 6;
    const int lr = l & 15, lg = l >> 4;
    const int wr = w >> 2, wc = w & 3;
    // XCD-chunked swizzle (192 = 8 XCDs x 24; region = 4 M-rows x 6 N-cols)
    const int wg = blockIdx.y * 12 + blockIdx.x;
    const int xcd = wg & 7, ii = wg >> 3;
    const int byp = (xcd >> 1) * 4 + ii / 6;
    const int bxp = (xcd & 1) * 6 + ii % 6;
    const int m0 = byp * 256, n0 = bxp * 256;
    const int nt = K >> 6, nh = nt << 2;

    const int sr0 = t >> 2;
    const int scc = ((t & 3) ^ ((sr0 >> 1) & 3)) * 8;
    const short* As0 = A + (size_t)(m0 + sr0) * K + scc;
    const short* As1 = A + (size_t)(m0 + sr0 + 128) * K + scc;
    const short* Bs0 = B + (size_t)(n0 + sr0) * K + scc;
    const short* Bs1 = B + (size_t)(n0 + sr0 + 128) * K + scc;
    short* ldsb = &lds[0][0][0];

    auto stageH = [&](int H) {
        int Tp = H >> 2, pos = H & 3;
        int kb = Tp * 64 + ((pos <= 1) ? 32 : 0);
        short* dst = ldsb + ((Tp & 1) * 4 + pos) * 8192 + t * 8;
        if (pos & 1) {
            gload16(As0 + kb, dst);
            gload16(As1 + kb, dst + 4096);
        } else {
            gload16(Bs0 + kb, dst);
            gload16(Bs1 + kb, dst + 4096);
        }
    };

    int aoff[8], boff[4];
    #pragma unroll
    for (int mi = 0; mi < 8; ++mi) {
        int row = wr * 128 + mi * 16 + lr;
        aoff[mi] = row * 32 + (lg ^ ((row >> 1) & 3)) * 8;
    }
    #pragma unroll
    for (int ni = 0; ni < 4; ++ni) {
        int row = wc * 64 + ni * 16 + lr;
        boff[ni] = row * 32 + (lg ^ ((row >> 1) & 3)) * 8;
    }

    f32x4 acc[8][4] = {};

    for (int H = 0; H < 7; ++H) stageH(H);
    asm volatile("s_waitcnt vmcnt(6)" ::: "memory");
    __builtin_amdgcn_s_barrier();

    for (int T = 0; T < nt; ++T) {
        const short* rbase = ldsb + (T & 1) * 32768;
        const short* B1b = rbase;
        const short* A1b = rbase + 8192;
        const short* B0b = rbase + 16384;
        const short* A0b = rbase + 24576;
        const int Hs = (T << 2) + 7;
        short8 a[4], b[4];

        // ---- phase 0: k[32:64), m0-3 ----
        #pragma unroll
        for (int i = 0; i < 4; ++i) a[i] = *(const short8*)(A1b + aoff[i]);
        #pragma unroll
        for (int i = 0; i < 4; ++i) b[i] = *(const short8*)(B1b + boff[i]);
        if (Hs < nh) stageH(Hs);
        __builtin_amdgcn_sched_barrier(0);
        __builtin_amdgcn_s_barrier();
        asm volatile("s_waitcnt lgkmcnt(0)" ::: "memory");
        __builtin_amdgcn_sched_barrier(0);
        __builtin_amdgcn_s_setprio(1);
        #pragma unroll
        for (int mi = 0; mi < 4; ++mi)
            #pragma unroll
            for (int ni = 0; ni < 4; ++ni)
                acc[mi][ni] = MFMA16(a[mi], b[ni], acc[mi][ni]);
        __builtin_amdgcn_s_setprio(0);
        __builtin_amdgcn_sched_barrier(0);
        __builtin_amdgcn_s_barrier();

        // ---- phase 1: k[32:64), m4-7 ----
        #pragma unroll
        for (int i = 0; i < 4; ++i) a[i] = *(const short8*)(A1b + aoff[4 + i]);
        if (Hs + 1 < nh) stageH(Hs + 1);
        __builtin_amdgcn_sched_barrier(0);
        __builtin_amdgcn_s_barrier();
        asm volatile("s_waitcnt lgkmcnt(0)" ::: "memory");
        __builtin_amdgcn_sched_barrier(0);
        __builtin_amdgcn_s_setprio(1);
        #pragma unroll
        for (int mi = 0; mi < 4; ++mi)
            #pragma unroll
            for (int ni = 0; ni < 4; ++ni)
                acc[4 + mi][ni] = MFMA16(a[mi], b[ni], acc[4 + mi][ni]);
        __builtin_amdgcn_s_setprio(0);
        __builtin_amdgcn_sched_barrier(0);
        __builtin_amdgcn_s_barrier();

        // ---- phase 2: k[0:32), m0-3 ----
        #pragma unroll
        for (int i = 0; i < 4; ++i) a[i] = *(const short8*)(A0b + aoff[i]);
        #pragma unroll
        for (int i = 0; i < 4; ++i) b[i] = *(const short8*)(B0b + boff[i]);
        if (Hs + 2 < nh) stageH(Hs + 2);
        __builtin_amdgcn_sched_barrier(0);
        __builtin_amdgcn_s_barrier();
        asm volatile("s_waitcnt lgkmcnt(0)" ::: "memory");
        __builtin_amdgcn_sched_barrier(0);
        __builtin_amdgcn_s_setprio(1);
        #pragma unroll
        for (int mi = 0; mi < 4; ++mi)
            #pragma unroll
            for (int ni = 0; ni < 4; ++ni)
                acc[mi][ni] = MFMA16(a[mi], b[ni], acc[mi][ni]);
        __builtin_amdgcn_s_setprio(0);
        __builtin_amdgcn_sched_barrier(0);
        __builtin_amdgcn_s_barrier();

        // ---- phase 3: k[0:32), m4-7 ----
        #pragma unroll
        for (int i = 0; i < 4; ++i) a[i] = *(const short8*)(A0b + aoff[4 + i]);
        if (Hs + 3 < nh) stageH(Hs + 3);
        __builtin_amdgcn_sched_barrier(0);
        __builtin_amdgcn_s_barrier();
        asm volatile("s_waitcnt lgkmcnt(0)" ::: "memory");
        __builtin_amdgcn_sched_barrier(0);
        __builtin_amdgcn_s_setprio(1);
        #pragma unroll
        for (int mi = 0; mi < 4; ++mi)
            #pragma unroll
            for (int ni = 0; ni < 4; ++ni)
                acc[4 + mi][ni] = MFMA16(a[mi], b[ni], acc[4 + mi][ni]);
        __builtin_amdgcn_s_setprio(0);
        if (T < nt - 2) {
            asm volatile("s_waitcnt vmcnt(6)" ::: "memory");
        } else if (T == nt - 2) {
            asm volatile("s_waitcnt vmcnt(0)" ::: "memory");
        }
        __builtin_amdgcn_sched_barrier(0);
        __builtin_amdgcn_s_barrier();
    }

    if (VFUSE && n0 >= 2048) {
        // V region: write transposed to vt[(b*16+h)*64 + d][s], s = row index
        #pragma unroll
        for (int mi = 0; mi < 8; ++mi)
            #pragma unroll
            for (int ni = 0; ni < 4; ++ni) {
                int nn = n0 + wc * 64 + ni * 16 + lr;
                int h = (nn - 2048) >> 6, dd = (nn - 2048) & 63;
                int mm = m0 + wr * 128 + mi * 16 + lg * 4;
                int bb = mm >> 11, s = mm & 2047;
                short4v ov;
                #pragma unroll
                for (int rr = 0; rr < 4; ++rr) ov[rr] = f2bf(acc[mi][ni][rr]);
                *(short4v*)(vt + ((size_t)(bb * 16 + h) * 64 + dd) * 2048 + s) = ov;
            }
        return;
    }
    const float qs = (QSCALE && n0 < 1024) ? 1.4426950408889634f : 1.0f;
    #pragma unroll
    for (int mi = 0; mi < 8; ++mi)
        #pragma unroll
        for (int ni = 0; ni < 4; ++ni)
            #pragma unroll
            for (int rr = 0; rr < 4; ++rr) {
                int mm = m0 + wr * 128 + mi * 16 + lg * 4 + rr;
                int nn = n0 + wc * 64 + ni * 16 + lr;
                float v = acc[mi][ni][rr] * qs;
                if (OUT_BF16) ((short*)Cout)[(size_t)mm * N + nn] = f2bf(v);
                else ((float*)Cout)[(size_t)mm * N + nn] = v;
            }
}

// C[M,N] = A[M,K] * B[N,K]^T, bf16 in, fp32 accum (m97 structure) — for gemm2.
// XCD-chunked swizzle: grid must be 8x32 (256 blocks); each XCD owns a
// 4Mx8N region (1 MB A + 2 MB B < 4 MB L2).
template <int OUT_BF16>
__global__ __launch_bounds__(256) void gemm_bt(const short* __restrict__ A,
                                               const short* __restrict__ B,
                                               void* __restrict__ Cout,
                                               int M, int N, int K) {
    __shared__ short sA[4096];
    __shared__ short sB[4096];
    const int t = threadIdx.x;
    const int l = t & 63, w = t >> 6;
    const int lr = l & 15, lg = l >> 4;
    // swizzle: 256 = 8 XCDs x 32; region = 4 M-rows x 8 N-cols
    const int wg = blockIdx.y * 8 + blockIdx.x;
    const int xcd = wg & 7, ii = wg >> 3;
    const int m0 = (xcd * 4 + (ii >> 3)) * 128, n0 = (ii & 7) * 128;
    const int wm = (w >> 1) * 64, wn = (w & 1) * 64;
    const int c0 = w * 64 + l, c1 = c0 + 256;
    const short* Ap0 = A + (size_t)(m0 + (c0 >> 2)) * K + (c0 & 3) * 8;
    const short* Ap1 = A + (size_t)(m0 + (c1 >> 2)) * K + (c1 & 3) * 8;
    const short* Bp0 = B + (size_t)(n0 + (c0 >> 2)) * K + (c0 & 3) * 8;
    const short* Bp1 = B + (size_t)(n0 + (c1 >> 2)) * K + (c1 & 3) * 8;
    short* lA0 = sA + w * 512;
    short* lA1 = sA + 2048 + w * 512;
    short* lB0 = sB + w * 512;
    short* lB1 = sB + 2048 + w * 512;
    f32x4 acc[4][4] = {};
    for (int k0 = 0; k0 < K; k0 += 32) {
        gload16(Ap0 + k0, lA0);
        gload16(Ap1 + k0, lA1);
        gload16(Bp0 + k0, lB0);
        gload16(Bp1 + k0, lB1);
        __syncthreads();
        short8 af[4], bfr[4];
        #pragma unroll
        for (int m = 0; m < 4; ++m) af[m] = *(const short8*)&sA[(wm + m * 16 + lr) * 32 + lg * 8];
        #pragma unroll
        for (int n = 0; n < 4; ++n) bfr[n] = *(const short8*)&sB[(wn + n * 16 + lr) * 32 + lg * 8];
        #pragma unroll
        for (int m = 0; m < 4; ++m)
            #pragma unroll
            for (int n = 0; n < 4; ++n)
                acc[m][n] = MFMA16(af[m], bfr[n], acc[m][n]);
        __syncthreads();
    }
    #pragma unroll
    for (int m = 0; m < 4; ++m)
        #pragma unroll
        for (int n = 0; n < 4; ++n)
            #pragma unroll
            for (int r = 0; r < 4; ++r) {
                int mm = m0 + wm + m * 16 + lg * 4 + r;
                int nn = n0 + wn + n * 16 + lr;
                float v = acc[m][n][r];
                if (OUT_BF16) ((short*)Cout)[(size_t)mm * N + nn] = f2bf(v);
                else ((float*)Cout)[(size_t)mm * N + nn] = v;
            }
}

// Flash attention, swapped-QK^T, exp2 domain. 8 waves x 16 q-rows (q-tile 128),
// single K/V LDS buffer, grid 512 (2/CU, 16 waves/CU), XCD-chunked swizzle
// (each XCD owns 4 contiguous bh -> K/V L2-resident). Best measured: 62.9 us.
__global__ __launch_bounds__(512, 4) void attn_kernel(const short* __restrict__ qkv,
                                                      const short* __restrict__ vt,
                                                      const int* __restrict__ amask,
                                                      const float* __restrict__ rel_bias,
                                                      short* __restrict__ xout) {
    __shared__ float tbl[340];       // bias*log2e for j-i in [-168,168]
    __shared__ short sK[4096];       // [key 64][dk 64], XOR-swizzled chunks
    __shared__ short sV[4096];       // [d 64][key 64], XOR-swizzled chunks
    __shared__ short sP[8][16][72];  // per-wave P^T
    __shared__ int mflags[32];       // per-64-key-tile all-nonzero flags
    const int t = threadIdx.x;       // 0..511
    const int l = t & 63, w = t >> 6;
    const int lr = l & 15, lg = l >> 4;
    const int wg = blockIdx.y * 16 + blockIdx.x;
    const int swz = (wg & 7) * 64 + (wg >> 3);
    const int qt = swz & 15, bh = swz >> 4;
    const int b = bh >> 4, h = bh & 15;
    const int q0 = qt * 128 + w * 16;
    const float LOG2E = 1.4426950408889634f;

    if (t < 32) mflags[t] = ~0;
    if (t < 337) {
        int idx = t;
        int d = idx - 168;
        int a = d < 0 ? -d : d;
        int fb = a < 8 ? a
                 : (a < 12 ? 8 : a < 16 ? 9 : a < 23 ? 10 : a < 32 ? 11
                    : a < 46 ? 12 : a < 64 ? 13 : a < 91 ? 14 : 15);
        int bk = (d > 0 ? 16 : 0) + fb;
        tbl[idx] = rel_bias[bk * 16 + h] * LOG2E;
    }
    const float rbp = rel_bias[31 * 16 + h] * LOG2E;  // d >= 91
    const float rbn = rel_bias[15 * 16 + h] * LOG2E;  // d <= -91

    short8 qf[2];
    #pragma unroll
    for (int ds = 0; ds < 2; ++ds)
        qf[ds] = *(const short8*)(qkv + (size_t)(b * 2048 + q0 + lr) * 3072 + h * 64 + ds * 32 + lg * 8);

    const int4 ma = ((const int4*)(amask + b * 2048))[t];

    const int srow = t >> 3;
    const int scp = ((t & 7) ^ (srow & 7)) * 8;
    const short* kgp = qkv + (size_t)(b * 2048 + srow) * 3072 + 1024 + h * 64 + scp;
    const short* vgp = vt + ((size_t)bh * 64 + srow) * 2048 + scp;
    short* dK = sK + t * 8;
    short* dV = sV + t * 8;
    const int sw8 = (lr & 7) * 8;
    const int ibb = -q0 + lg * 4 - lr + 168;

    __syncthreads();  // mflags init visible
    int mok = ma.x & ma.y & ma.z & ma.w;
    if (mok == 0) atomicAnd(&mflags[t >> 4], 0);

    f32x4 o[4] = {};
    float mreg = -1e30f, lreg = 0.f;

    for (int kt = 0; kt < 2048; kt += 64) {
        gload16(kgp + (size_t)kt * 3072, dK);
        gload16(vgp + kt, dV);
        __syncthreads();  // stage drained (+ atomicAnd visible on first iter)

        f32x4 pe[4];
        #pragma unroll
        for (int ct = 0; ct < 4; ++ct) {
            f32x4 z = {};
            #pragma unroll
            for (int ds = 0; ds < 2; ++ds) {
                short8 kf = *(const short8*)&sK[(ct * 16 + lr) * 64 + ((ds * 32 + lg * 8) ^ sw8)];
                z = MFMA16(kf, qf[ds], z);
            }
            pe[ct] = z;
        }

        float cb;
        if (kt >= q0 + 106) {
            cb = rbp;
        } else if (kt + 63 <= q0 - 91) {
            cb = rbn;
        } else {
            cb = 0.f;
            const int ib = kt + ibb;
            #pragma unroll
            for (int ct = 0; ct < 4; ++ct)
                #pragma unroll
                for (int r = 0; r < 4; ++r)
                    pe[ct][r] += tbl[ib + ct * 16 + r];
        }

        float t0 = fmaxf(fmaxf(pe[0][0], pe[0][1]), fmaxf(pe[0][2], pe[0][3]));
        float t1 = fmaxf(fmaxf(pe[1][0], pe[1][1]), fmaxf(pe[1][2], pe[1][3]));
        float t2 = fmaxf(fmaxf(pe[2][0], pe[2][1]), fmaxf(pe[2][2], pe[2][3]));
        float t3 = fmaxf(fmaxf(pe[3][0], pe[3][1]), fmaxf(pe[3][2], pe[3][3]));
        float lmax = fmaxf(fmaxf(t0, t1), fmaxf(t2, t3));
        if (__any(lmax > mreg - cb + 11.5f)) {
            float rm = fmaxf(lmax, __shfl_xor(lmax, 16));
            rm = fmaxf(rm, __shfl_xor(rm, 32));
            float mnew = fmaxf(mreg, rm + cb);
            float alpha = fexp2(mreg - mnew);
            lreg *= alpha;
            #pragma unroll
            for (int dt = 0; dt < 4; ++dt)
                #pragma unroll
                for (int r = 0; r < 4; ++r)
                    o[dt][r] *= alpha;
            mreg = mnew;
        }
        const float madj = mreg - cb;
        const int tok = mflags[kt >> 6];
        float rs = 0.f;
        if (tok) {
            #pragma unroll
            for (int ct = 0; ct < 4; ++ct) {
                float p[4];
                #pragma unroll
                for (int r = 0; r < 4; ++r) {
                    float pv = fexp2(pe[ct][r] - madj);
                    p[r] = pv;
                    rs += pv;
                }
                uint2v pk;
                pk[0] = cvt_pk_bf16(p[0], p[1]);
                pk[1] = cvt_pk_bf16(p[2], p[3]);
                *(uint2v*)&sP[w][lr][ct * 16 + lg * 4] = pk;
            }
        } else {
            const int4* mp = (const int4*)(amask + b * 2048 + kt);
            #pragma unroll
            for (int ct = 0; ct < 4; ++ct) {
                int4 cm = mp[ct * 4 + lg];
                float p[4];
                #pragma unroll
                for (int r = 0; r < 4; ++r) {
                    float pv = fexp2(pe[ct][r] - madj);
                    pv = ((const int*)&cm)[r] ? pv : 0.f;
                    p[r] = pv;
                    rs += pv;
                }
                uint2v pk;
                pk[0] = cvt_pk_bf16(p[0], p[1]);
                pk[1] = cvt_pk_bf16(p[2], p[3]);
                *(uint2v*)&sP[w][lr][ct * 16 + lg * 4] = pk;
            }
        }
        lreg += rs;

        #pragma unroll
        for (int kk = 0; kk < 2; ++kk) {
            short8 pf = *(const short8*)&sP[w][lr][kk * 32 + lg * 8];
            #pragma unroll
            for (int dt = 0; dt < 4; ++dt) {
                short8 vf = *(const short8*)&sV[(dt * 16 + lr) * 64 + ((kk * 32 + lg * 8) ^ sw8)];
                o[dt] = MFMA16(vf, pf, o[dt]);
            }
        }
        __syncthreads();  // all waves done with sK/sV before next stage
    }

    float lsum = lreg + __shfl_xor(lreg, 16);
    lsum += __shfl_xor(lsum, 32);
    const float inv = 1.0f / lsum;
    #pragma unroll
    for (int dt = 0; dt < 4; ++dt) {
        short4v ov;
        #pragma unroll
        for (int r = 0; r < 4; ++r) ov[r] = f2bf(o[dt][r] * inv);
        *(short4v*)(xout + (size_t)(b * 2048 + q0 + lr) * 1024 + h * 64 + dt * 16 + lg * 4) = ov;
    }
}

extern "C" void kernel_launch(void* const* d_in, const int* in_sizes, int n_in,
                              void* d_out, int out_size, void* d_ws, size_t ws_size,
                              hipStream_t stream) {
    const float* hidden = (const float*)d_in[0];
    const int* amask = (const int*)d_in[1];
    const float* w_qkv = (const float*)d_in[2];
    const float* rel_bias = (const float*)d_in[3];
    const float* w_o = (const float*)d_in[4];
    if (ws_size < 58720256) return;
    char* ws = (char*)d_ws;
    short* hidden_bf = (short*)(ws + 0);
    short* wqkv_bf   = (short*)(ws + 8388608);
    short* wo_bf     = (short*)(ws + 14680064);
    short* qkv       = (short*)(ws + 16777216);
    short* vt        = (short*)(ws + 41943040);
    short* xbuf      = (short*)(ws + 50331648);

    cast_all<<<4096, 256, 0, stream>>>(hidden, w_qkv, w_o, hidden_bf, wqkv_bf, wo_bf);
    gemm8p<1, 1, 1><<<dim3(12, 16), 512, 0, stream>>>(hidden_bf, wqkv_bf, qkv, vt, 4096, 3072, 1024);
    attn_kernel<<<dim3(16, 32), 512, 0, stream>>>(qkv, vt, amask, rel_bias, xbuf);
    gemm_bt<0><<<dim3(8, 32), 256, 0, stream>>>(xbuf, wo_bf, d_out, 4096, 1024, 1024);
}

// Round 22
// 123.916 us; speedup vs baseline: 1.0853x; 1.0403x over previous
//
#include <hip/hip_runtime.h>
#include <stdint.h>

typedef __attribute__((ext_vector_type(4))) float f32x4;
typedef __attribute__((ext_vector_type(8))) short short8;
typedef __attribute__((ext_vector_type(4))) short short4v;
typedef __attribute__((ext_vector_type(2))) unsigned uint2v;

__device__ __forceinline__ short f2bf(float f) {
    union { float f; unsigned u; } x; x.f = f;
    return (short)((x.u + 0x7fffu + ((x.u >> 16) & 1u)) >> 16);
}

__device__ __forceinline__ unsigned cvt_pk_bf16(float lo, float hi) {
    unsigned r;
    asm("v_cvt_pk_bf16_f32 %0, %1, %2" : "=v"(r) : "v"(lo), "v"(hi));
    return r;
}

__device__ __forceinline__ float fexp2(float x) {
#if __has_builtin(__builtin_amdgcn_exp2f)
    return __builtin_amdgcn_exp2f(x);
#else
    return exp2f(x);
#endif
}

#define MFMA16(a, b, c) __builtin_amdgcn_mfma_f32_16x16x32_bf16((a), (b), (c), 0, 0, 0)

__device__ __forceinline__ void gload16(const void* g, void* l) {
    __builtin_amdgcn_global_load_lds((const __attribute__((address_space(1))) void*)g,
                                     (__attribute__((address_space(3))) void*)l, 16, 0, 0);
}

// all three f32->bf16 casts in one launch
__global__ __launch_bounds__(256) void cast_all(const float* __restrict__ h,
                                                const float* __restrict__ wq,
                                                const float* __restrict__ wo,
                                                short* __restrict__ hb,
                                                short* __restrict__ wqb,
                                                short* __restrict__ wob) {
    int i = blockIdx.x * 256 + threadIdx.x;  // 1048576 chunks of 8
    const float* s;
    short* d;
    int j;
    if (i < 524288) { s = h; d = hb; j = i; }
    else if (i < 917504) { s = wq; d = wqb; j = i - 524288; }
    else { s = wo; d = wob; j = i - 917504; }
    float4 a = ((const float4*)s)[j * 2];
    float4 b = ((const float4*)s)[j * 2 + 1];
    short8 o;
    o[0] = f2bf(a.x); o[1] = f2bf(a.y); o[2] = f2bf(a.z); o[3] = f2bf(a.w);
    o[4] = f2bf(b.x); o[5] = f2bf(b.y); o[6] = f2bf(b.z); o[7] = f2bf(b.w);
    ((short8*)d)[j] = o;
}

// ------------- 4-phase 256x192 GEMM (C = A * B^T), exact grid fill -------------
// Grid MUST be 16x16 = 256 blocks (1/CU). XCD-chunked: region 4Mx8N (~5 MB).
// Per-fragment QSCALE (cols<1024 * log2e) and VFUSE (cols>=2048 -> vt transposed).
__global__ __launch_bounds__(512, 2) void gemm192(const short* __restrict__ A,
                                                  const short* __restrict__ B,
                                                  short* __restrict__ Cout,
                                                  short* __restrict__ vt,
                                                  int M, int N, int K) {
    // LDS: per buffer A 16384 shorts + B 12288 shorts = 28672; dbuf = 112 KB
    __shared__ short lds[2][28672];
    const int t = threadIdx.x;
    const int l = t & 63, w = t >> 6;
    const int lr = l & 15, lg = l >> 4;
    const int wr = w >> 2, wc = w & 3;
    // XCD swizzle: 256 = 8 XCDs x 32; region = 4 M-tiles x 8 N-tiles
    const int wg = blockIdx.y * 16 + blockIdx.x;
    const int xcd = wg & 7, ii = wg >> 3;
    const int m0 = ((xcd >> 1) * 4 + (ii >> 3)) * 256;
    const int n0 = ((xcd & 1) * 8 + (ii & 7)) * 192;
    const int nt = K >> 6;

    // staging sources: row = t>>3 (+64 strides), col chunk pre-swizzled by row&7
    const int srow = t >> 3;
    const int sc = ((t & 7) ^ (srow & 7)) * 8;
    const short* Ab = A + (size_t)(m0 + srow) * K + sc;
    const short* Bb = B + (size_t)(n0 + srow) * K + sc;
    const size_t rK64 = (size_t)64 * K;

    // fragment read offsets (shorts): row*64 + ((kh*4+lg)^(row&7))*8
    int aoff[2][8], boff[2][3];
    #pragma unroll
    for (int mi = 0; mi < 8; ++mi) {
        int row = wr * 128 + mi * 16 + lr;
        aoff[0][mi] = row * 64 + ((lg ^ (row & 7)) * 8);
        aoff[1][mi] = row * 64 + (((4 + lg) ^ (row & 7)) * 8);
    }
    #pragma unroll
    for (int ni = 0; ni < 3; ++ni) {
        int row = wc * 48 + ni * 16 + lr;
        boff[0][ni] = row * 64 + ((lg ^ (row & 7)) * 8);
        boff[1][ni] = row * 64 + (((4 + lg) ^ (row & 7)) * 8);
    }

    f32x4 acc[8][3] = {};

    // prologue: stage tile 0 fully, drain, barrier
    {
        short* dA = &lds[0][0] + t * 8;
        short* dB = &lds[0][16384] + t * 8;
        gload16(Bb, dB);
        gload16(Bb + rK64, dB + 4096);
        gload16(Bb + 2 * rK64, dB + 8192);
        gload16(Ab, dA);
        gload16(Ab + rK64, dA + 4096);
        gload16(Ab + 2 * rK64, dA + 8192);
        gload16(Ab + 3 * rK64, dA + 12288);
    }
    asm volatile("s_waitcnt vmcnt(0)" ::: "memory");
    __builtin_amdgcn_s_barrier();

    for (int T = 0; T < nt; ++T) {
        const short* Abuf = &lds[T & 1][0];
        const short* Bbuf = &lds[T & 1][16384];
        short* nA = &lds[(T & 1) ^ 1][0] + t * 8;
        short* nB = &lds[(T & 1) ^ 1][16384] + t * 8;
        const bool more = (T + 1 < nt);
        const int kb = (T + 1) * 64;
        short8 a[4], b[3];

        // ---- phase 0: kh1, m0-3 ----
        #pragma unroll
        for (int i = 0; i < 4; ++i) a[i] = *(const short8*)(Abuf + aoff[1][i]);
        #pragma unroll
        for (int i = 0; i < 3; ++i) b[i] = *(const short8*)(Bbuf + boff[1][i]);
        if (more) {  // stage next-tile B (3 loads) into buf^1
            gload16(Bb + kb, nB);
            gload16(Bb + rK64 + kb, nB + 4096);
            gload16(Bb + 2 * rK64 + kb, nB + 8192);
        }
        __builtin_amdgcn_sched_barrier(0);
        __builtin_amdgcn_s_barrier();
        asm volatile("s_waitcnt lgkmcnt(0)" ::: "memory");
        __builtin_amdgcn_sched_barrier(0);
        __builtin_amdgcn_s_setprio(1);
        #pragma unroll
        for (int mi = 0; mi < 4; ++mi)
            #pragma unroll
            for (int ni = 0; ni < 3; ++ni)
                acc[mi][ni] = MFMA16(a[mi], b[ni], acc[mi][ni]);
        __builtin_amdgcn_s_setprio(0);
        __builtin_amdgcn_sched_barrier(0);
        __builtin_amdgcn_s_barrier();

        // ---- phase 1: kh1, m4-7 ----
        #pragma unroll
        for (int i = 0; i < 4; ++i) a[i] = *(const short8*)(Abuf + aoff[1][4 + i]);
        if (more) {  // stage next-tile A rows 0-127 (2 loads)
            gload16(Ab + kb, nA);
            gload16(Ab + rK64 + kb, nA + 4096);
        }
        __builtin_amdgcn_sched_barrier(0);
        __builtin_amdgcn_s_barrier();
        asm volatile("s_waitcnt lgkmcnt(0)" ::: "memory");
        __builtin_amdgcn_sched_barrier(0);
        __builtin_amdgcn_s_setprio(1);
        #pragma unroll
        for (int mi = 0; mi < 4; ++mi)
            #pragma unroll
            for (int ni = 0; ni < 3; ++ni)
                acc[4 + mi][ni] = MFMA16(a[mi], b[ni], acc[4 + mi][ni]);
        __builtin_amdgcn_s_setprio(0);
        __builtin_amdgcn_sched_barrier(0);
        __builtin_amdgcn_s_barrier();

        // ---- phase 2: kh0, m0-3 ----
        #pragma unroll
        for (int i = 0; i < 4; ++i) a[i] = *(const short8*)(Abuf + aoff[0][i]);
        #pragma unroll
        for (int i = 0; i < 3; ++i) b[i] = *(const short8*)(Bbuf + boff[0][i]);
        if (more) {  // stage next-tile A rows 128-255 (2 loads)
            gload16(Ab + 2 * rK64 + kb, nA + 8192);
            gload16(Ab + 3 * rK64 + kb, nA + 12288);
        }
        __builtin_amdgcn_sched_barrier(0);
        __builtin_amdgcn_s_barrier();
        asm volatile("s_waitcnt lgkmcnt(0)" ::: "memory");
        __builtin_amdgcn_sched_barrier(0);
        __builtin_amdgcn_s_setprio(1);
        #pragma unroll
        for (int mi = 0; mi < 4; ++mi)
            #pragma unroll
            for (int ni = 0; ni < 3; ++ni)
                acc[mi][ni] = MFMA16(a[mi], b[ni], acc[mi][ni]);
        __builtin_amdgcn_s_setprio(0);
        __builtin_amdgcn_sched_barrier(0);
        __builtin_amdgcn_s_barrier();

        // ---- phase 3: kh0, m4-7 ----
        #pragma unroll
        for (int i = 0; i < 4; ++i) a[i] = *(const short8*)(Abuf + aoff[0][4 + i]);
        __builtin_amdgcn_sched_barrier(0);
        __builtin_amdgcn_s_barrier();
        asm volatile("s_waitcnt lgkmcnt(0)" ::: "memory");
        __builtin_amdgcn_sched_barrier(0);
        __builtin_amdgcn_s_setprio(1);
        #pragma unroll
        for (int mi = 0; mi < 4; ++mi)
            #pragma unroll
            for (int ni = 0; ni < 3; ++ni)
                acc[4 + mi][ni] = MFMA16(a[mi], b[ni], acc[4 + mi][ni]);
        __builtin_amdgcn_s_setprio(0);
        if (more) asm volatile("s_waitcnt vmcnt(0)" ::: "memory");  // next tile landed
        __builtin_amdgcn_sched_barrier(0);
        __builtin_amdgcn_s_barrier();
    }

    // epilogue: per-fragment region routing (Q: *log2e; K: plain; V: transposed vt)
    const float LOG2E = 1.4426950408889634f;
    #pragma unroll
    for (int mi = 0; mi < 8; ++mi)
        #pragma unroll
        for (int ni = 0; ni < 3; ++ni) {
            const int col0 = n0 + wc * 48 + ni * 16;
            const int mmb = m0 + wr * 128 + mi * 16 + lg * 4;
            if (col0 >= 2048) {
                // V: vt[(bb*16+h)*64 + dd][s]
                const int h = (col0 - 2048) >> 6;
                const int dd = ((col0 - 2048) & 63) + lr;
                const int bb = mmb >> 11, s = mmb & 2047;
                short4v ov;
                #pragma unroll
                for (int rr = 0; rr < 4; ++rr) ov[rr] = f2bf(acc[mi][ni][rr]);
                *(short4v*)(vt + ((size_t)(bb * 16 + h) * 64 + dd) * 2048 + s) = ov;
            } else {
                const float qs = (col0 < 1024) ? LOG2E : 1.0f;
                #pragma unroll
                for (int rr = 0; rr < 4; ++rr)
                    Cout[(size_t)(mmb + rr) * N + col0 + lr] = f2bf(acc[mi][ni][rr] * qs);
            }
        }
}

// C[M,N] = A[M,K] * B[N,K]^T, bf16 in, fp32 accum (m97 structure) — for gemm2.
// XCD-chunked swizzle: grid must be 8x32 (256 blocks); region 4Mx8N.
template <int OUT_BF16>
__global__ __launch_bounds__(256) void gemm_bt(const short* __restrict__ A,
                                               const short* __restrict__ B,
                                               void* __restrict__ Cout,
                                               int M, int N, int K) {
    __shared__ short sA[4096];
    __shared__ short sB[4096];
    const int t = threadIdx.x;
    const int l = t & 63, w = t >> 6;
    const int lr = l & 15, lg = l >> 4;
    const int wg = blockIdx.y * 8 + blockIdx.x;
    const int xcd = wg & 7, ii = wg >> 3;
    const int m0 = (xcd * 4 + (ii >> 3)) * 128, n0 = (ii & 7) * 128;
    const int wm = (w >> 1) * 64, wn = (w & 1) * 64;
    const int c0 = w * 64 + l, c1 = c0 + 256;
    const short* Ap0 = A + (size_t)(m0 + (c0 >> 2)) * K + (c0 & 3) * 8;
    const short* Ap1 = A + (size_t)(m0 + (c1 >> 2)) * K + (c1 & 3) * 8;
    const short* Bp0 = B + (size_t)(n0 + (c0 >> 2)) * K + (c0 & 3) * 8;
    const short* Bp1 = B + (size_t)(n0 + (c1 >> 2)) * K + (c1 & 3) * 8;
    short* lA0 = sA + w * 512;
    short* lA1 = sA + 2048 + w * 512;
    short* lB0 = sB + w * 512;
    short* lB1 = sB + 2048 + w * 512;
    f32x4 acc[4][4] = {};
    for (int k0 = 0; k0 < K; k0 += 32) {
        gload16(Ap0 + k0, lA0);
        gload16(Ap1 + k0, lA1);
        gload16(Bp0 + k0, lB0);
        gload16(Bp1 + k0, lB1);
        __syncthreads();
        short8 af[4], bfr[4];
        #pragma unroll
        for (int m = 0; m < 4; ++m) af[m] = *(const short8*)&sA[(wm + m * 16 + lr) * 32 + lg * 8];
        #pragma unroll
        for (int n = 0; n < 4; ++n) bfr[n] = *(const short8*)&sB[(wn + n * 16 + lr) * 32 + lg * 8];
        #pragma unroll
        for (int m = 0; m < 4; ++m)
            #pragma unroll
            for (int n = 0; n < 4; ++n)
                acc[m][n] = MFMA16(af[m], bfr[n], acc[m][n]);
        __syncthreads();
    }
    #pragma unroll
    for (int m = 0; m < 4; ++m)
        #pragma unroll
        for (int n = 0; n < 4; ++n)
            #pragma unroll
            for (int r = 0; r < 4; ++r) {
                int mm = m0 + wm + m * 16 + lg * 4 + r;
                int nn = n0 + wn + n * 16 + lr;
                float v = acc[m][n][r];
                if (OUT_BF16) ((short*)Cout)[(size_t)mm * N + nn] = f2bf(v);
                else ((float*)Cout)[(size_t)mm * N + nn] = v;
            }
}

// Flash attention, swapped-QK^T, exp2 domain. 8 waves x 16 q-rows (q-tile 128),
// single K/V LDS buffer, grid 512 (2/CU, 16 waves/CU), XCD-chunked swizzle.
// Best measured: 62.8 us.
__global__ __launch_bounds__(512, 4) void attn_kernel(const short* __restrict__ qkv,
                                                      const short* __restrict__ vt,
                                                      const int* __restrict__ amask,
                                                      const float* __restrict__ rel_bias,
                                                      short* __restrict__ xout) {
    __shared__ float tbl[340];       // bias*log2e for j-i in [-168,168]
    __shared__ short sK[4096];       // [key 64][dk 64], XOR-swizzled chunks
    __shared__ short sV[4096];       // [d 64][key 64], XOR-swizzled chunks
    __shared__ short sP[8][16][72];  // per-wave P^T
    __shared__ int mflags[32];       // per-64-key-tile all-nonzero flags
    const int t = threadIdx.x;       // 0..511
    const int l = t & 63, w = t >> 6;
    const int lr = l & 15, lg = l >> 4;
    const int wg = blockIdx.y * 16 + blockIdx.x;
    const int swz = (wg & 7) * 64 + (wg >> 3);
    const int qt = swz & 15, bh = swz >> 4;
    const int b = bh >> 4, h = bh & 15;
    const int q0 = qt * 128 + w * 16;
    const float LOG2E = 1.4426950408889634f;

    if (t < 32) mflags[t] = ~0;
    if (t < 337) {
        int idx = t;
        int d = idx - 168;
        int a = d < 0 ? -d : d;
        int fb = a < 8 ? a
                 : (a < 12 ? 8 : a < 16 ? 9 : a < 23 ? 10 : a < 32 ? 11
                    : a < 46 ? 12 : a < 64 ? 13 : a < 91 ? 14 : 15);
        int bk = (d > 0 ? 16 : 0) + fb;
        tbl[idx] = rel_bias[bk * 16 + h] * LOG2E;
    }
    const float rbp = rel_bias[31 * 16 + h] * LOG2E;  // d >= 91
    const float rbn = rel_bias[15 * 16 + h] * LOG2E;  // d <= -91

    short8 qf[2];
    #pragma unroll
    for (int ds = 0; ds < 2; ++ds)
        qf[ds] = *(const short8*)(qkv + (size_t)(b * 2048 + q0 + lr) * 3072 + h * 64 + ds * 32 + lg * 8);

    const int4 ma = ((const int4*)(amask + b * 2048))[t];

    const int srow = t >> 3;
    const int scp = ((t & 7) ^ (srow & 7)) * 8;
    const short* kgp = qkv + (size_t)(b * 2048 + srow) * 3072 + 1024 + h * 64 + scp;
    const short* vgp = vt + ((size_t)bh * 64 + srow) * 2048 + scp;
    short* dK = sK + t * 8;
    short* dV = sV + t * 8;
    const int sw8 = (lr & 7) * 8;
    const int ibb = -q0 + lg * 4 - lr + 168;

    __syncthreads();  // mflags init visible
    int mok = ma.x & ma.y & ma.z & ma.w;
    if (mok == 0) atomicAnd(&mflags[t >> 4], 0);

    f32x4 o[4] = {};
    float mreg = -1e30f, lreg = 0.f;

    for (int kt = 0; kt < 2048; kt += 64) {
        gload16(kgp + (size_t)kt * 3072, dK);
        gload16(vgp + kt, dV);
        __syncthreads();  // stage drained (+ atomicAnd visible on first iter)

        f32x4 pe[4];
        #pragma unroll
        for (int ct = 0; ct < 4; ++ct) {
            f32x4 z = {};
            #pragma unroll
            for (int ds = 0; ds < 2; ++ds) {
                short8 kf = *(const short8*)&sK[(ct * 16 + lr) * 64 + ((ds * 32 + lg * 8) ^ sw8)];
                z = MFMA16(kf, qf[ds], z);
            }
            pe[ct] = z;
        }

        float cb;
        if (kt >= q0 + 106) {
            cb = rbp;
        } else if (kt + 63 <= q0 - 91) {
            cb = rbn;
        } else {
            cb = 0.f;
            const int ib = kt + ibb;
            #pragma unroll
            for (int ct = 0; ct < 4; ++ct)
                #pragma unroll
                for (int r = 0; r < 4; ++r)
                    pe[ct][r] += tbl[ib + ct * 16 + r];
        }

        float t0 = fmaxf(fmaxf(pe[0][0], pe[0][1]), fmaxf(pe[0][2], pe[0][3]));
        float t1 = fmaxf(fmaxf(pe[1][0], pe[1][1]), fmaxf(pe[1][2], pe[1][3]));
        float t2 = fmaxf(fmaxf(pe[2][0], pe[2][1]), fmaxf(pe[2][2], pe[2][3]));
        float t3 = fmaxf(fmaxf(pe[3][0], pe[3][1]), fmaxf(pe[3][2], pe[3][3]));
        float lmax = fmaxf(fmaxf(t0, t1), fmaxf(t2, t3));
        if (__any(lmax > mreg - cb + 11.5f)) {
            float rm = fmaxf(lmax, __shfl_xor(lmax, 16));
            rm = fmaxf(rm, __shfl_xor(rm, 32));
            float mnew = fmaxf(mreg, rm + cb);
            float alpha = fexp2(mreg - mnew);
            lreg *= alpha;
            #pragma unroll
            for (int dt = 0; dt < 4; ++dt)
                #pragma unroll
                for (int r = 0; r < 4; ++r)
                    o[dt][r] *= alpha;
            mreg = mnew;
        }
        const float madj = mreg - cb;
        const int tok = mflags[kt >> 6];
        float rs = 0.f;
        if (tok) {
            #pragma unroll
            for (int ct = 0; ct < 4; ++ct) {
                float p[4];
                #pragma unroll
                for (int r = 0; r < 4; ++r) {
                    float pv = fexp2(pe[ct][r] - madj);
                    p[r] = pv;
                    rs += pv;
                }
                uint2v pk;
                pk[0] = cvt_pk_bf16(p[0], p[1]);
                pk[1] = cvt_pk_bf16(p[2], p[3]);
                *(uint2v*)&sP[w][lr][ct * 16 + lg * 4] = pk;
            }
        } else {
            const int4* mp = (const int4*)(amask + b * 2048 + kt);
            #pragma unroll
            for (int ct = 0; ct < 4; ++ct) {
                int4 cm = mp[ct * 4 + lg];
                float p[4];
                #pragma unroll
                for (int r = 0; r < 4; ++r) {
                    float pv = fexp2(pe[ct][r] - madj);
                    pv = ((const int*)&cm)[r] ? pv : 0.f;
                    p[r] = pv;
                    rs += pv;
                }
                uint2v pk;
                pk[0] = cvt_pk_bf16(p[0], p[1]);
                pk[1] = cvt_pk_bf16(p[2], p[3]);
                *(uint2v*)&sP[w][lr][ct * 16 + lg * 4] = pk;
            }
        }
        lreg += rs;

        #pragma unroll
        for (int kk = 0; kk < 2; ++kk) {
            short8 pf = *(const short8*)&sP[w][lr][kk * 32 + lg * 8];
            #pragma unroll
            for (int dt = 0; dt < 4; ++dt) {
                short8 vf = *(const short8*)&sV[(dt * 16 + lr) * 64 + ((kk * 32 + lg * 8) ^ sw8)];
                o[dt] = MFMA16(vf, pf, o[dt]);
            }
        }
        __syncthreads();  // all waves done with sK/sV before next stage
    }

    float lsum = lreg + __shfl_xor(lreg, 16);
    lsum += __shfl_xor(lsum, 32);
    const float inv = 1.0f / lsum;
    #pragma unroll
    for (int dt = 0; dt < 4; ++dt) {
        short4v ov;
        #pragma unroll
        for (int r = 0; r < 4; ++r) ov[r] = f2bf(o[dt][r] * inv);
        *(short4v*)(xout + (size_t)(b * 2048 + q0 + lr) * 1024 + h * 64 + dt * 16 + lg * 4) = ov;
    }
}

extern "C" void kernel_launch(void* const* d_in, const int* in_sizes, int n_in,
                              void* d_out, int out_size, void* d_ws, size_t ws_size,
                              hipStream_t stream) {
    const float* hidden = (const float*)d_in[0];
    const int* amask = (const int*)d_in[1];
    const float* w_qkv = (const float*)d_in[2];
    const float* rel_bias = (const float*)d_in[3];
    const float* w_o = (const float*)d_in[4];
    if (ws_size < 58720256) return;
    char* ws = (char*)d_ws;
    short* hidden_bf = (short*)(ws + 0);
    short* wqkv_bf   = (short*)(ws + 8388608);
    short* wo_bf     = (short*)(ws + 14680064);
    short* qkv       = (short*)(ws + 16777216);
    short* vt        = (short*)(ws + 41943040);
    short* xbuf      = (short*)(ws + 50331648);

    cast_all<<<4096, 256, 0, stream>>>(hidden, w_qkv, w_o, hidden_bf, wqkv_bf, wo_bf);
    gemm192<<<dim3(16, 16), 512, 0, stream>>>(hidden_bf, wqkv_bf, qkv, vt, 4096, 3072, 1024);
    attn_kernel<<<dim3(16, 32), 512, 0, stream>>>(qkv, vt, amask, rel_bias, xbuf);
    gemm_bt<0><<<dim3(8, 32), 256, 0, stream>>>(xbuf, wo_bf, d_out, 4096, 1024, 1024);
}

// Round 23
// 113.178 us; speedup vs baseline: 1.1883x; 1.0949x over previous
//
#include <hip/hip_runtime.h>
#include <stdint.h>

typedef __attribute__((ext_vector_type(4))) float f32x4;
typedef __attribute__((ext_vector_type(8))) short short8;
typedef __attribute__((ext_vector_type(4))) short short4v;
typedef __attribute__((ext_vector_type(2))) unsigned uint2v;

__device__ __forceinline__ short f2bf(float f) {
    union { float f; unsigned u; } x; x.f = f;
    return (short)((x.u + 0x7fffu + ((x.u >> 16) & 1u)) >> 16);
}

__device__ __forceinline__ unsigned cvt_pk_bf16(float lo, float hi) {
    unsigned r;
    asm("v_cvt_pk_bf16_f32 %0, %1, %2" : "=v"(r) : "v"(lo), "v"(hi));
    return r;
}

__device__ __forceinline__ float fexp2(float x) {
#if __has_builtin(__builtin_amdgcn_exp2f)
    return __builtin_amdgcn_exp2f(x);
#else
    return exp2f(x);
#endif
}

#define MFMA16(a, b, c) __builtin_amdgcn_mfma_f32_16x16x32_bf16((a), (b), (c), 0, 0, 0)

__device__ __forceinline__ void gload16(const void* g, void* l) {
    __builtin_amdgcn_global_load_lds((const __attribute__((address_space(1))) void*)g,
                                     (__attribute__((address_space(3))) void*)l, 16, 0, 0);
}

// all three f32->bf16 casts in one launch
__global__ __launch_bounds__(256) void cast_all(const float* __restrict__ h,
                                                const float* __restrict__ wq,
                                                const float* __restrict__ wo,
                                                short* __restrict__ hb,
                                                short* __restrict__ wqb,
                                                short* __restrict__ wob) {
    int i = blockIdx.x * 256 + threadIdx.x;  // 1048576 chunks of 8
    const float* s;
    short* d;
    int j;
    if (i < 524288) { s = h; d = hb; j = i; }
    else if (i < 917504) { s = wq; d = wqb; j = i - 524288; }
    else { s = wo; d = wob; j = i - 917504; }
    float4 a = ((const float4*)s)[j * 2];
    float4 b = ((const float4*)s)[j * 2 + 1];
    short8 o;
    o[0] = f2bf(a.x); o[1] = f2bf(a.y); o[2] = f2bf(a.z); o[3] = f2bf(a.w);
    o[4] = f2bf(b.x); o[5] = f2bf(b.y); o[6] = f2bf(b.z); o[7] = f2bf(b.w);
    ((short8*)d)[j] = o;
}

// ------------- 4-phase 256x192 GEMM (C = A * B^T), exact grid fill -------------
// Grid MUST be 16x16 = 256 blocks (1/CU). XCD-chunked: region 4Mx8N (~5 MB).
// Per-fragment QSCALE (cols<1024 * log2e) and VFUSE (cols>=2048 -> vt transposed).
__global__ __launch_bounds__(512, 2) void gemm192(const short* __restrict__ A,
                                                  const short* __restrict__ B,
                                                  short* __restrict__ Cout,
                                                  short* __restrict__ vt,
                                                  int M, int N, int K) {
    // LDS: per buffer A 16384 shorts + B 12288 shorts = 28672; dbuf = 112 KB
    __shared__ short lds[2][28672];
    const int t = threadIdx.x;
    const int l = t & 63, w = t >> 6;
    const int lr = l & 15, lg = l >> 4;
    const int wr = w >> 2, wc = w & 3;
    // XCD swizzle: 256 = 8 XCDs x 32; region = 4 M-tiles x 8 N-tiles
    const int wg = blockIdx.y * 16 + blockIdx.x;
    const int xcd = wg & 7, ii = wg >> 3;
    const int m0 = ((xcd >> 1) * 4 + (ii >> 3)) * 256;
    const int n0 = ((xcd & 1) * 8 + (ii & 7)) * 192;
    const int nt = K >> 6;

    // staging sources: row = t>>3 (+64 strides), col chunk pre-swizzled by row&7
    const int srow = t >> 3;
    const int sc = ((t & 7) ^ (srow & 7)) * 8;
    const short* Ab = A + (size_t)(m0 + srow) * K + sc;
    const short* Bb = B + (size_t)(n0 + srow) * K + sc;
    const size_t rK64 = (size_t)64 * K;

    // fragment read offsets (shorts): row*64 + ((kh*4+lg)^(row&7))*8
    int aoff[2][8], boff[2][3];
    #pragma unroll
    for (int mi = 0; mi < 8; ++mi) {
        int row = wr * 128 + mi * 16 + lr;
        aoff[0][mi] = row * 64 + ((lg ^ (row & 7)) * 8);
        aoff[1][mi] = row * 64 + (((4 + lg) ^ (row & 7)) * 8);
    }
    #pragma unroll
    for (int ni = 0; ni < 3; ++ni) {
        int row = wc * 48 + ni * 16 + lr;
        boff[0][ni] = row * 64 + ((lg ^ (row & 7)) * 8);
        boff[1][ni] = row * 64 + (((4 + lg) ^ (row & 7)) * 8);
    }

    f32x4 acc[8][3] = {};

    // prologue: stage tile 0 fully, drain, barrier
    {
        short* dA = &lds[0][0] + t * 8;
        short* dB = &lds[0][16384] + t * 8;
        gload16(Bb, dB);
        gload16(Bb + rK64, dB + 4096);
        gload16(Bb + 2 * rK64, dB + 8192);
        gload16(Ab, dA);
        gload16(Ab + rK64, dA + 4096);
        gload16(Ab + 2 * rK64, dA + 8192);
        gload16(Ab + 3 * rK64, dA + 12288);
    }
    asm volatile("s_waitcnt vmcnt(0)" ::: "memory");
    __builtin_amdgcn_s_barrier();

    for (int T = 0; T < nt; ++T) {
        const short* Abuf = &lds[T & 1][0];
        const short* Bbuf = &lds[T & 1][16384];
        short* nA = &lds[(T & 1) ^ 1][0] + t * 8;
        short* nB = &lds[(T & 1) ^ 1][16384] + t * 8;
        const bool more = (T + 1 < nt);
        const int kb = (T + 1) * 64;
        short8 a[4], b[3];

        // ---- phase 0: kh1, m0-3 ----
        #pragma unroll
        for (int i = 0; i < 4; ++i) a[i] = *(const short8*)(Abuf + aoff[1][i]);
        #pragma unroll
        for (int i = 0; i < 3; ++i) b[i] = *(const short8*)(Bbuf + boff[1][i]);
        if (more) {  // stage next-tile B (3 loads) into buf^1
            gload16(Bb + kb, nB);
            gload16(Bb + rK64 + kb, nB + 4096);
            gload16(Bb + 2 * rK64 + kb, nB + 8192);
        }
        __builtin_amdgcn_sched_barrier(0);
        __builtin_amdgcn_s_barrier();
        asm volatile("s_waitcnt lgkmcnt(0)" ::: "memory");
        __builtin_amdgcn_sched_barrier(0);
        __builtin_amdgcn_s_setprio(1);
        #pragma unroll
        for (int mi = 0; mi < 4; ++mi)
            #pragma unroll
            for (int ni = 0; ni < 3; ++ni)
                acc[mi][ni] = MFMA16(a[mi], b[ni], acc[mi][ni]);
        __builtin_amdgcn_s_setprio(0);
        __builtin_amdgcn_sched_barrier(0);
        __builtin_amdgcn_s_barrier();

        // ---- phase 1: kh1, m4-7 ----
        #pragma unroll
        for (int i = 0; i < 4; ++i) a[i] = *(const short8*)(Abuf + aoff[1][4 + i]);
        if (more) {  // stage next-tile A rows 0-127 (2 loads)
            gload16(Ab + kb, nA);
            gload16(Ab + rK64 + kb, nA + 4096);
        }
        __builtin_amdgcn_sched_barrier(0);
        __builtin_amdgcn_s_barrier();
        asm volatile("s_waitcnt lgkmcnt(0)" ::: "memory");
        __builtin_amdgcn_sched_barrier(0);
        __builtin_amdgcn_s_setprio(1);
        #pragma unroll
        for (int mi = 0; mi < 4; ++mi)
            #pragma unroll
            for (int ni = 0; ni < 3; ++ni)
                acc[4 + mi][ni] = MFMA16(a[mi], b[ni], acc[4 + mi][ni]);
        __builtin_amdgcn_s_setprio(0);
        __builtin_amdgcn_sched_barrier(0);
        __builtin_amdgcn_s_barrier();

        // ---- phase 2: kh0, m0-3 ----
        #pragma unroll
        for (int i = 0; i < 4; ++i) a[i] = *(const short8*)(Abuf + aoff[0][i]);
        #pragma unroll
        for (int i = 0; i < 3; ++i) b[i] = *(const short8*)(Bbuf + boff[0][i]);
        if (more) {  // stage next-tile A rows 128-255 (2 loads)
            gload16(Ab + 2 * rK64 + kb, nA + 8192);
            gload16(Ab + 3 * rK64 + kb, nA + 12288);
        }
        __builtin_amdgcn_sched_barrier(0);
        __builtin_amdgcn_s_barrier();
        asm volatile("s_waitcnt lgkmcnt(0)" ::: "memory");
        __builtin_amdgcn_sched_barrier(0);
        __builtin_amdgcn_s_setprio(1);
        #pragma unroll
        for (int mi = 0; mi < 4; ++mi)
            #pragma unroll
            for (int ni = 0; ni < 3; ++ni)
                acc[mi][ni] = MFMA16(a[mi], b[ni], acc[mi][ni]);
        __builtin_amdgcn_s_setprio(0);
        __builtin_amdgcn_sched_barrier(0);
        __builtin_amdgcn_s_barrier();

        // ---- phase 3: kh0, m4-7 ----
        #pragma unroll
        for (int i = 0; i < 4; ++i) a[i] = *(const short8*)(Abuf + aoff[0][4 + i]);
        __builtin_amdgcn_sched_barrier(0);
        __builtin_amdgcn_s_barrier();
        asm volatile("s_waitcnt lgkmcnt(0)" ::: "memory");
        __builtin_amdgcn_sched_barrier(0);
        __builtin_amdgcn_s_setprio(1);
        #pragma unroll
        for (int mi = 0; mi < 4; ++mi)
            #pragma unroll
            for (int ni = 0; ni < 3; ++ni)
                acc[4 + mi][ni] = MFMA16(a[mi], b[ni], acc[4 + mi][ni]);
        __builtin_amdgcn_s_setprio(0);
        if (more) asm volatile("s_waitcnt vmcnt(0)" ::: "memory");  // next tile landed
        __builtin_amdgcn_sched_barrier(0);
        __builtin_amdgcn_s_barrier();
    }

    // epilogue: per-fragment region routing (Q: *log2e; K: plain; V: transposed vt)
    const float LOG2E = 1.4426950408889634f;
    #pragma unroll
    for (int mi = 0; mi < 8; ++mi)
        #pragma unroll
        for (int ni = 0; ni < 3; ++ni) {
            const int col0 = n0 + wc * 48 + ni * 16;
            const int mmb = m0 + wr * 128 + mi * 16 + lg * 4;
            if (col0 >= 2048) {
                // V: vt[(bb*16+h)*64 + dd][s]
                const int h = (col0 - 2048) >> 6;
                const int dd = ((col0 - 2048) & 63) + lr;
                const int bb = mmb >> 11, s = mmb & 2047;
                short4v ov;
                #pragma unroll
                for (int rr = 0; rr < 4; ++rr) ov[rr] = f2bf(acc[mi][ni][rr]);
                *(short4v*)(vt + ((size_t)(bb * 16 + h) * 64 + dd) * 2048 + s) = ov;
            } else {
                const float qs = (col0 < 1024) ? LOG2E : 1.0f;
                #pragma unroll
                for (int rr = 0; rr < 4; ++rr)
                    Cout[(size_t)(mmb + rr) * N + col0 + lr] = f2bf(acc[mi][ni][rr] * qs);
            }
        }
}

// gemm2: C[M,N] = A[M,K] * B[N,K]^T, fp32 out. 128x128 tile, BK=64,
// LDS double-buffer + counted vmcnt + raw barriers (gemm8p recipe).
// Grid must be 8x32 (256 blocks, 1/CU); XCD region 4Mx8N.
__global__ __launch_bounds__(256, 2) void gemm2k(const short* __restrict__ A,
                                                 const short* __restrict__ B,
                                                 float* __restrict__ Cout,
                                                 int M, int N, int K) {
    __shared__ short lds[2][16384];  // per buf: A 128x64 + B 128x64 = 16384 shorts
    const int t = threadIdx.x;
    const int l = t & 63, w = t >> 6;
    const int lr = l & 15, lg = l >> 4;
    const int wg = blockIdx.y * 8 + blockIdx.x;
    const int xcd = wg & 7, ii = wg >> 3;
    const int m0 = (xcd * 4 + (ii >> 3)) * 128, n0 = (ii & 7) * 128;
    const int wm = (w >> 1) * 64, wn = (w & 1) * 64;
    const int nt = K >> 6;

    // staging: 1024 chunks per matrix; thread t owns chunks {t,+256,+512,+768};
    // row = c>>3 (0..127), col chunk pre-swizzled by row&7 ((row+32)&7==row&7)
    const int srow = t >> 3;
    const int sc = ((t & 7) ^ (srow & 7)) * 8;
    const short* Ab = A + (size_t)(m0 + srow) * K + sc;
    const short* Bb = B + (size_t)(n0 + srow) * K + sc;
    const size_t rK32 = (size_t)32 * K;

    int aoff[2][4], boff[2][4];
    #pragma unroll
    for (int i = 0; i < 4; ++i) {
        int ra = wm + i * 16 + lr;
        int rb = wn + i * 16 + lr;
        aoff[0][i] = ra * 64 + ((lg ^ (ra & 7)) * 8);
        aoff[1][i] = ra * 64 + (((4 + lg) ^ (ra & 7)) * 8);
        boff[0][i] = rb * 64 + ((lg ^ (rb & 7)) * 8);
        boff[1][i] = rb * 64 + (((4 + lg) ^ (rb & 7)) * 8);
    }

    f32x4 acc[4][4] = {};

    // prologue: stage tile 0 (8 loads), drain, barrier
    {
        short* dA = &lds[0][0] + t * 8;
        short* dB = &lds[0][8192] + t * 8;
        gload16(Ab, dA);
        gload16(Ab + rK32, dA + 2048);
        gload16(Ab + 2 * rK32, dA + 4096);
        gload16(Ab + 3 * rK32, dA + 6144);
        gload16(Bb, dB);
        gload16(Bb + rK32, dB + 2048);
        gload16(Bb + 2 * rK32, dB + 4096);
        gload16(Bb + 3 * rK32, dB + 6144);
    }
    asm volatile("s_waitcnt vmcnt(0)" ::: "memory");
    __builtin_amdgcn_s_barrier();

    for (int T = 0; T < nt; ++T) {
        const short* Abuf = &lds[T & 1][0];
        const short* Bbuf = &lds[T & 1][8192];
        if (T + 1 < nt) {  // stage next tile; loads stay in flight across barrier
            const int kb = (T + 1) * 64;
            short* nA = &lds[(T & 1) ^ 1][0] + t * 8;
            short* nB = &lds[(T & 1) ^ 1][8192] + t * 8;
            gload16(Ab + kb, nA);
            gload16(Ab + rK32 + kb, nA + 2048);
            gload16(Ab + 2 * rK32 + kb, nA + 4096);
            gload16(Ab + 3 * rK32 + kb, nA + 6144);
            gload16(Bb + kb, nB);
            gload16(Bb + rK32 + kb, nB + 2048);
            gload16(Bb + 2 * rK32 + kb, nB + 4096);
            gload16(Bb + 3 * rK32 + kb, nB + 6144);
            asm volatile("s_waitcnt vmcnt(8)" ::: "memory");  // tile-T landed
        } else {
            asm volatile("s_waitcnt vmcnt(0)" ::: "memory");
        }
        __builtin_amdgcn_sched_barrier(0);
        __builtin_amdgcn_s_barrier();
        __builtin_amdgcn_sched_barrier(0);

        #pragma unroll
        for (int kh = 0; kh < 2; ++kh) {
            short8 af[4], bf8[4];
            #pragma unroll
            for (int i = 0; i < 4; ++i) af[i] = *(const short8*)(Abuf + aoff[kh][i]);
            #pragma unroll
            for (int i = 0; i < 4; ++i) bf8[i] = *(const short8*)(Bbuf + boff[kh][i]);
            __builtin_amdgcn_s_setprio(1);
            #pragma unroll
            for (int m = 0; m < 4; ++m)
                #pragma unroll
                for (int n = 0; n < 4; ++n)
                    acc[m][n] = MFMA16(af[m], bf8[n], acc[m][n]);
            __builtin_amdgcn_s_setprio(0);
        }
        __builtin_amdgcn_sched_barrier(0);
        __builtin_amdgcn_s_barrier();  // all waves done with buf[T&1]
        __builtin_amdgcn_sched_barrier(0);
    }

    #pragma unroll
    for (int m = 0; m < 4; ++m)
        #pragma unroll
        for (int n = 0; n < 4; ++n)
            #pragma unroll
            for (int r = 0; r < 4; ++r) {
                int mm = m0 + wm + m * 16 + lg * 4 + r;
                int nn = n0 + wn + n * 16 + lr;
                Cout[(size_t)mm * N + nn] = acc[m][n][r];
            }
}

// Flash attention, swapped-QK^T, exp2 domain. 8 waves x 16 q-rows (q-tile 128),
// single K/V LDS buffer, grid 512 (2/CU, 16 waves/CU), XCD-chunked swizzle.
// Best measured: 62.8 us.
__global__ __launch_bounds__(512, 4) void attn_kernel(const short* __restrict__ qkv,
                                                      const short* __restrict__ vt,
                                                      const int* __restrict__ amask,
                                                      const float* __restrict__ rel_bias,
                                                      short* __restrict__ xout) {
    __shared__ float tbl[340];       // bias*log2e for j-i in [-168,168]
    __shared__ short sK[4096];       // [key 64][dk 64], XOR-swizzled chunks
    __shared__ short sV[4096];       // [d 64][key 64], XOR-swizzled chunks
    __shared__ short sP[8][16][72];  // per-wave P^T
    __shared__ int mflags[32];       // per-64-key-tile all-nonzero flags
    const int t = threadIdx.x;       // 0..511
    const int l = t & 63, w = t >> 6;
    const int lr = l & 15, lg = l >> 4;
    const int wg = blockIdx.y * 16 + blockIdx.x;
    const int swz = (wg & 7) * 64 + (wg >> 3);
    const int qt = swz & 15, bh = swz >> 4;
    const int b = bh >> 4, h = bh & 15;
    const int q0 = qt * 128 + w * 16;
    const float LOG2E = 1.4426950408889634f;

    if (t < 32) mflags[t] = ~0;
    if (t < 337) {
        int idx = t;
        int d = idx - 168;
        int a = d < 0 ? -d : d;
        int fb = a < 8 ? a
                 : (a < 12 ? 8 : a < 16 ? 9 : a < 23 ? 10 : a < 32 ? 11
                    : a < 46 ? 12 : a < 64 ? 13 : a < 91 ? 14 : 15);
        int bk = (d > 0 ? 16 : 0) + fb;
        tbl[idx] = rel_bias[bk * 16 + h] * LOG2E;
    }
    const float rbp = rel_bias[31 * 16 + h] * LOG2E;  // d >= 91
    const float rbn = rel_bias[15 * 16 + h] * LOG2E;  // d <= -91

    short8 qf[2];
    #pragma unroll
    for (int ds = 0; ds < 2; ++ds)
        qf[ds] = *(const short8*)(qkv + (size_t)(b * 2048 + q0 + lr) * 3072 + h * 64 + ds * 32 + lg * 8);

    const int4 ma = ((const int4*)(amask + b * 2048))[t];

    const int srow = t >> 3;
    const int scp = ((t & 7) ^ (srow & 7)) * 8;
    const short* kgp = qkv + (size_t)(b * 2048 + srow) * 3072 + 1024 + h * 64 + scp;
    const short* vgp = vt + ((size_t)bh * 64 + srow) * 2048 + scp;
    short* dK = sK + t * 8;
    short* dV = sV + t * 8;
    const int sw8 = (lr & 7) * 8;
    const int ibb = -q0 + lg * 4 - lr + 168;

    __syncthreads();  // mflags init visible
    int mok = ma.x & ma.y & ma.z & ma.w;
    if (mok == 0) atomicAnd(&mflags[t >> 4], 0);

    f32x4 o[4] = {};
    float mreg = -1e30f, lreg = 0.f;

    for (int kt = 0; kt < 2048; kt += 64) {
        gload16(kgp + (size_t)kt * 3072, dK);
        gload16(vgp + kt, dV);
        __syncthreads();  // stage drained (+ atomicAnd visible on first iter)

        f32x4 pe[4];
        #pragma unroll
        for (int ct = 0; ct < 4; ++ct) {
            f32x4 z = {};
            #pragma unroll
            for (int ds = 0; ds < 2; ++ds) {
                short8 kf = *(const short8*)&sK[(ct * 16 + lr) * 64 + ((ds * 32 + lg * 8) ^ sw8)];
                z = MFMA16(kf, qf[ds], z);
            }
            pe[ct] = z;
        }

        float cb;
        if (kt >= q0 + 106) {
            cb = rbp;
        } else if (kt + 63 <= q0 - 91) {
            cb = rbn;
        } else {
            cb = 0.f;
            const int ib = kt + ibb;
            #pragma unroll
            for (int ct = 0; ct < 4; ++ct)
                #pragma unroll
                for (int r = 0; r < 4; ++r)
                    pe[ct][r] += tbl[ib + ct * 16 + r];
        }

        float t0 = fmaxf(fmaxf(pe[0][0], pe[0][1]), fmaxf(pe[0][2], pe[0][3]));
        float t1 = fmaxf(fmaxf(pe[1][0], pe[1][1]), fmaxf(pe[1][2], pe[1][3]));
        float t2 = fmaxf(fmaxf(pe[2][0], pe[2][1]), fmaxf(pe[2][2], pe[2][3]));
        float t3 = fmaxf(fmaxf(pe[3][0], pe[3][1]), fmaxf(pe[3][2], pe[3][3]));
        float lmax = fmaxf(fmaxf(t0, t1), fmaxf(t2, t3));
        if (__any(lmax > mreg - cb + 11.5f)) {
            float rm = fmaxf(lmax, __shfl_xor(lmax, 16));
            rm = fmaxf(rm, __shfl_xor(rm, 32));
            float mnew = fmaxf(mreg, rm + cb);
            float alpha = fexp2(mreg - mnew);
            lreg *= alpha;
            #pragma unroll
            for (int dt = 0; dt < 4; ++dt)
                #pragma unroll
                for (int r = 0; r < 4; ++r)
                    o[dt][r] *= alpha;
            mreg = mnew;
        }
        const float madj = mreg - cb;
        const int tok = mflags[kt >> 6];
        float rs = 0.f;
        if (tok) {
            #pragma unroll
            for (int ct = 0; ct < 4; ++ct) {
                float p[4];
                #pragma unroll
                for (int r = 0; r < 4; ++r) {
                    float pv = fexp2(pe[ct][r] - madj);
                    p[r] = pv;
                    rs += pv;
                }
                uint2v pk;
                pk[0] = cvt_pk_bf16(p[0], p[1]);
                pk[1] = cvt_pk_bf16(p[2], p[3]);
                *(uint2v*)&sP[w][lr][ct * 16 + lg * 4] = pk;
            }
        } else {
            const int4* mp = (const int4*)(amask + b * 2048 + kt);
            #pragma unroll
            for (int ct = 0; ct < 4; ++ct) {
                int4 cm = mp[ct * 4 + lg];
                float p[4];
                #pragma unroll
                for (int r = 0; r < 4; ++r) {
                    float pv = fexp2(pe[ct][r] - madj);
                    pv = ((const int*)&cm)[r] ? pv : 0.f;
                    p[r] = pv;
                    rs += pv;
                }
                uint2v pk;
                pk[0] = cvt_pk_bf16(p[0], p[1]);
                pk[1] = cvt_pk_bf16(p[2], p[3]);
                *(uint2v*)&sP[w][lr][ct * 16 + lg * 4] = pk;
            }
        }
        lreg += rs;

        #pragma unroll
        for (int kk = 0; kk < 2; ++kk) {
            short8 pf = *(const short8*)&sP[w][lr][kk * 32 + lg * 8];
            #pragma unroll
            for (int dt = 0; dt < 4; ++dt) {
                short8 vf = *(const short8*)&sV[(dt * 16 + lr) * 64 + ((kk * 32 + lg * 8) ^ sw8)];
                o[dt] = MFMA16(vf, pf, o[dt]);
            }
        }
        __syncthreads();  // all waves done with sK/sV before next stage
    }

    float lsum = lreg + __shfl_xor(lreg, 16);
    lsum += __shfl_xor(lsum, 32);
    const float inv = 1.0f / lsum;
    #pragma unroll
    for (int dt = 0; dt < 4; ++dt) {
        short4v ov;
        #pragma unroll
        for (int r = 0; r < 4; ++r) ov[r] = f2bf(o[dt][r] * inv);
        *(short4v*)(xout + (size_t)(b * 2048 + q0 + lr) * 1024 + h * 64 + dt * 16 + lg * 4) = ov;
    }
}

extern "C" void kernel_launch(void* const* d_in, const int* in_sizes, int n_in,
                              void* d_out, int out_size, void* d_ws, size_t ws_size,
                              hipStream_t stream) {
    const float* hidden = (const float*)d_in[0];
    const int* amask = (const int*)d_in[1];
    const float* w_qkv = (const float*)d_in[2];
    const float* rel_bias = (const float*)d_in[3];
    const float* w_o = (const float*)d_in[4];
    if (ws_size < 58720256) return;
    char* ws = (char*)d_ws;
    short* hidden_bf = (short*)(ws + 0);
    short* wqkv_bf   = (short*)(ws + 8388608);
    short* wo_bf     = (short*)(ws + 14680064);
    short* qkv       = (short*)(ws + 16777216);
    short* vt        = (short*)(ws + 41943040);
    short* xbuf      = (short*)(ws + 50331648);

    cast_all<<<4096, 256, 0, stream>>>(hidden, w_qkv, w_o, hidden_bf, wqkv_bf, wo_bf);
    gemm192<<<dim3(16, 16), 512, 0, stream>>>(hidden_bf, wqkv_bf, qkv, vt, 4096, 3072, 1024);
    attn_kernel<<<dim3(16, 32), 512, 0, stream>>>(qkv, vt, amask, rel_bias, xbuf);
    gemm2k<<<dim3(8, 32), 256, 0, stream>>>(xbuf, wo_bf, (float*)d_out, 4096, 1024, 1024);
}